// Round 7
// baseline (3763.123 us; speedup 1.0000x reference)
//
#include <hip/hip_runtime.h>
#include <hip/hip_cooperative_groups.h>
#include <math.h>

namespace cg = cooperative_groups;

// AttentionOCR: B=512, P=64, CIN=512, HID=512, EMB=512, NCLS=96, T=30
static constexpr int BATCH = 512;
static constexpr int PPOS  = 64;
static constexpr int HIDC  = 512;

typedef __attribute__((ext_vector_type(8))) short bf8;   // 8 bf16 = 4 VGPRs
typedef __attribute__((ext_vector_type(4))) short bfv4;  // 4 bf16 = 2 VGPRs
typedef __attribute__((ext_vector_type(4))) float f4;

static __device__ __forceinline__ float sigmoidf_(float x) { return 1.f / (1.f + expf(-x)); }

static __device__ __forceinline__ short f2bf(float x) {
  unsigned u = __float_as_uint(x);
  u = u + 0x7FFF + ((u >> 16) & 1);   // round-nearest-even to bf16
  return (short)(u >> 16);
}
static __device__ __forceinline__ float bf2f(short s) {
  return __uint_as_float(((unsigned)(unsigned short)s) << 16);
}

// ---------------- strided transpose: dst[C x R], dst[c][r] = src[r*ld + c] ----------------
__global__ void transpose_k(const float* __restrict__ src, float* __restrict__ dst, int R, int C, int ld) {
  __shared__ float tile[32][33];
  int c0 = blockIdx.x * 32, r0 = blockIdx.y * 32;
  int x = threadIdx.x;
  for (int yy = threadIdx.y; yy < 32; yy += 8) {
    int r = r0 + yy, c = c0 + x;
    if (r < R && c < C) tile[yy][x] = src[(size_t)r * ld + c];
  }
  __syncthreads();
  for (int yy = threadIdx.y; yy < 32; yy += 8) {
    int c = c0 + yy, r = r0 + x;
    if (r < R && c < C) dst[(size_t)c * R + r] = tile[x][yy];
  }
}

// ---- fp32 GEMM (setup only): C[MxN]=A[MxK]@B[KxN](+bias), dbuf, 1 barrier/tile ----
template <bool BIAS>
__global__ __launch_bounds__(256) void gemm64_k(const float* __restrict__ A, const float* __restrict__ Bm,
                                                const float* __restrict__ bias, float* __restrict__ C,
                                                int M, int N, int K) {
  __shared__ float As[2][16][68];
  __shared__ float Bs[2][16][64];
  int tid = threadIdx.x;
  int tx = tid & 15, ty = tid >> 4;
  int row0 = blockIdx.y * 64, col0 = blockIdx.x * 64;
  int ar = tid >> 2, ak = (tid & 3) * 4;
  int bkb = tid >> 4, bn = (tid & 15) * 4;
  const float* Aptr = A + (size_t)(row0 + ar) * K + ak;
  const float* Bptr = Bm + (size_t)bkb * N + col0 + bn;
  float4 av = *(const float4*)Aptr;
  float4 bv = *(const float4*)Bptr;
  float acc[4][4] = {};
  int NT = K / 16;
  for (int kt = 0; kt < NT; kt++) {
    int buf = kt & 1;
    As[buf][ak + 0][ar] = av.x; As[buf][ak + 1][ar] = av.y;
    As[buf][ak + 2][ar] = av.z; As[buf][ak + 3][ar] = av.w;
    *(float4*)&Bs[buf][bkb][bn] = bv;
    if (kt + 1 < NT) {
      Aptr += 16; Bptr += (size_t)16 * N;
      av = *(const float4*)Aptr;
      bv = *(const float4*)Bptr;
    }
    __syncthreads();
#pragma unroll
    for (int q = 0; q < 16; q++) {
      float4 a4 = *(const float4*)&As[buf][q][ty * 4];
      float4 b4 = *(const float4*)&Bs[buf][q][tx * 4];
      acc[0][0] += a4.x * b4.x; acc[0][1] += a4.x * b4.y; acc[0][2] += a4.x * b4.z; acc[0][3] += a4.x * b4.w;
      acc[1][0] += a4.y * b4.x; acc[1][1] += a4.y * b4.y; acc[1][2] += a4.y * b4.z; acc[1][3] += a4.y * b4.w;
      acc[2][0] += a4.z * b4.x; acc[2][1] += a4.z * b4.y; acc[2][2] += a4.z * b4.z; acc[2][3] += a4.z * b4.w;
      acc[3][0] += a4.w * b4.x; acc[3][1] += a4.w * b4.y; acc[3][2] += a4.w * b4.z; acc[3][3] += a4.w * b4.w;
    }
  }
#pragma unroll
  for (int i = 0; i < 4; i++)
#pragma unroll
    for (int j = 0; j < 4; j++) {
      int rr = row0 + ty * 4 + i, cc = col0 + tx * 4 + j;
      float v = acc[i][j];
      if (BIAS) v += bias[cc];
      C[(size_t)rr * N + cc] = v;
    }
}

// ---------------- bfused[n] = bih[n] + bhh[n] + dot(Wih[n,:], bc) ----------------
__global__ void bfuse_k(const float* __restrict__ Wih, const float* __restrict__ bc,
                        const float* __restrict__ bih, const float* __restrict__ bhh,
                        float* __restrict__ bf) {
  int n = blockIdx.x * 256 + threadIdx.x;  // < 2048
  float s = bih[n] + bhh[n];
  const float* w = Wih + (size_t)n * 512;
  for (int m = 0; m < 512; m++) s += w[m] * bc[m];
  bf[n] = s;
}

// ---- BTg[2048 cp][1024 k] bf16 hi/lo: BTg[cp][k] = Bcat[k][cp], cp = j*4+g gate-interleaved ----
__global__ void build_btg_k(const float* __restrict__ tmp, const float* __restrict__ Whh,
                            short* __restrict__ hi, short* __restrict__ lo) {
  int idx = blockIdx.x * 256 + threadIdx.x;  // < 2048*1024
  int cp = idx >> 10, k = idx & 1023;
  int j = cp >> 2, g = cp & 3;
  int n = g * 512 + j;
  float v = (k < 512) ? tmp[(size_t)(512 + k) * 2048 + n] : Whh[(size_t)n * 512 + (k - 512)];
  short h = f2bf(v);
  hi[idx] = h;
  lo[idx] = f2bf(v - bf2f(h));
}

// ---- split fp32 -> bf16 hi/lo ----
__global__ void split_k(const float* __restrict__ src, short* __restrict__ hi, short* __restrict__ lo, int n) {
  int i = blockIdx.x * 256 + threadIdx.x;
  if (i < n) {
    float x = src[i];
    short h = f2bf(x);
    hi[i] = h;
    lo[i] = f2bf(x - bf2f(h));
  }
}

// ---------------- Gemb_p[96 x 2048] = (emb_table @ tmp[0:512]) + bfused, columns permuted ----------------
__global__ __launch_bounds__(256) void gemb_k(const float* __restrict__ emb_table, const float* __restrict__ tmp,
                                              const float* __restrict__ bfused, float* __restrict__ Gemb_p) {
  __shared__ float emb_s[4][512];
  int tid = threadIdx.x;
  int n0 = blockIdx.x * 256;
  int e0 = blockIdx.y * 4;
  for (int i = tid; i < 2048; i += 256)
    emb_s[i >> 9][i & 511] = emb_table[(size_t)(e0 + (i >> 9)) * 512 + (i & 511)];
  __syncthreads();
  int n = n0 + tid;
  float acc[4] = {};
  for (int k = 0; k < 512; k++) {
    float w = tmp[(size_t)k * 2048 + n];
#pragma unroll
    for (int e = 0; e < 4; e++) acc[e] += emb_s[e][k] * w;
  }
  int cp = (n & 511) * 4 + (n >> 9);
  float b = bfused[n];
#pragma unroll
  for (int e = 0; e < 4; e++) Gemb_p[(size_t)(e0 + e) * 2048 + cp] = acc[e] + b;
}

// ---------------- Za[96 x 512] = emb_table @ WaT_emb + ba ----------------
__global__ __launch_bounds__(256) void za_k(const float* __restrict__ emb_table, const float* __restrict__ WaT_emb,
                                            const float* __restrict__ ba, float* __restrict__ Za) {
  __shared__ float emb_s[4][512];
  int tid = threadIdx.x;
  int n0 = blockIdx.x * 256;
  int e0 = blockIdx.y * 4;
  for (int i = tid; i < 2048; i += 256)
    emb_s[i >> 9][i & 511] = emb_table[(size_t)(e0 + (i >> 9)) * 512 + (i & 511)];
  __syncthreads();
  int n = n0 + tid;
  float acc[4] = {};
  for (int k = 0; k < 512; k++) {
    float w = WaT_emb[(size_t)k * 512 + n];
#pragma unroll
    for (int e = 0; e < 4; e++) acc[e] += emb_s[e][k] * w;
  }
  float b = ba[n];
#pragma unroll
  for (int e = 0; e < 4; e++) Za[(size_t)(e0 + e) * 512 + n] = acc[e] + b;
}

// ---- feats: C[32768x512] = features @ Wfc^T (+bfc). XCD/temporal-swizzled linear grid (4096). ----
__global__ __launch_bounds__(256) void feats_mfma_k(const float* __restrict__ A,
                                                    const short* __restrict__ BTh, const short* __restrict__ BTl,
                                                    const float* __restrict__ bias, float* __restrict__ C) {
  __shared__ short Ah[2][64][40], Al[2][64][40], Bh[2][64][40], Bl[2][64][40];
  int blk = blockIdx.x;
  int xt = (blk >> 3) & 7;
  int ytile = (blk >> 6) * 8 + (blk & 7);
  int row0 = ytile * 64, col0 = xt * 64;
  int tid = threadIdx.x;
  int lane = tid & 63, wave = tid >> 6;
  int wm = (wave & 1) * 32, wn = (wave >> 1) * 32;
  int r15 = lane & 15, q8 = (lane >> 4) * 8;
  int sm = tid >> 2, sk = (tid & 3) * 8;
  const float* Ap = A + (size_t)(row0 + sm) * 512 + sk;
  const short* Bhp = BTh + (size_t)(col0 + sm) * 512 + sk;
  const short* Blp = BTl + (size_t)(col0 + sm) * 512 + sk;
  float4 a0 = *(const float4*)Ap, a1 = *(const float4*)(Ap + 4);
  bf8 bh = *(const bf8*)Bhp, bl = *(const bf8*)Blp;
  f4 acc[2][2] = {};
  for (int kt = 0; kt < 16; kt++) {
    int buf = kt & 1;
    {
      float av[8] = {a0.x, a0.y, a0.z, a0.w, a1.x, a1.y, a1.z, a1.w};
      bf8 ahv, alv;
#pragma unroll
      for (int i = 0; i < 8; i++) {
        short h = f2bf(av[i]);
        ahv[i] = h;
        alv[i] = f2bf(av[i] - bf2f(h));
      }
      *(bf8*)&Ah[buf][sm][sk] = ahv;
      *(bf8*)&Al[buf][sm][sk] = alv;
      *(bf8*)&Bh[buf][sm][sk] = bh;
      *(bf8*)&Bl[buf][sm][sk] = bl;
    }
    if (kt + 1 < 16) {
      Ap += 32; Bhp += 32; Blp += 32;
      a0 = *(const float4*)Ap; a1 = *(const float4*)(Ap + 4);
      bh = *(const bf8*)Bhp; bl = *(const bf8*)Blp;
    }
    __syncthreads();
    bf8 fah[2], fal[2], fbh[2], fbl[2];
#pragma unroll
    for (int r = 0; r < 2; r++) {
      fah[r] = *(const bf8*)&Ah[buf][wm + r * 16 + r15][q8];
      fal[r] = *(const bf8*)&Al[buf][wm + r * 16 + r15][q8];
    }
#pragma unroll
    for (int c = 0; c < 2; c++) {
      fbh[c] = *(const bf8*)&Bh[buf][wn + c * 16 + r15][q8];
      fbl[c] = *(const bf8*)&Bl[buf][wn + c * 16 + r15][q8];
    }
#pragma unroll
    for (int r = 0; r < 2; r++)
#pragma unroll
      for (int c = 0; c < 2; c++) {
        acc[r][c] = __builtin_amdgcn_mfma_f32_16x16x32_bf16(fah[r], fbh[c], acc[r][c], 0, 0, 0);
        acc[r][c] = __builtin_amdgcn_mfma_f32_16x16x32_bf16(fal[r], fbh[c], acc[r][c], 0, 0, 0);
        acc[r][c] = __builtin_amdgcn_mfma_f32_16x16x32_bf16(fah[r], fbl[c], acc[r][c], 0, 0, 0);
      }
  }
#pragma unroll
  for (int r = 0; r < 2; r++)
#pragma unroll
    for (int c = 0; c < 2; c++) {
      int col = col0 + wn + c * 16 + r15;
      float bv = bias[col];
#pragma unroll
      for (int i = 0; i < 4; i++) {
        int row = row0 + wm + r * 16 + (lane >> 4) * 4 + i;
        C[(size_t)row * 512 + col] = acc[r][c][i] + bv;
      }
    }
}

// ================= step phase bodies (shared by cooperative kernel and fallback) =================
// smem budget: 58368 bytes.

// attn: 2 batch rows per block (b0 = blk*2), 512 threads. Validated R3/R4 body.
__device__ void attn_body(char* smem, int blk, int t, int T,
                          const int* __restrict__ targets, const float* __restrict__ WaT_h,
                          const float* __restrict__ Za, const float* __restrict__ feats,
                          const float* __restrict__ h_prev, float* __restrict__ ctx) {
  float (*h_s)[512]     = (float(*)[512])(smem);           // 4096
  float (*zred)[2][512] = (float(*)[2][512])(smem + 4096); // 16384
  float (*z_s)[512]     = (float(*)[512])(smem + 20480);   // 4096
  float* redm           = (float*)(smem + 24576);          // 32
  float* reds           = (float*)(smem + 24608);          // 32
  float (*sc_s)[64]     = (float(*)[64])(smem + 24640);    // 512
  float (*w_s)[64]      = (float(*)[64])(smem + 25152);    // 512
  int tid = threadIdx.x;
  int wid = tid >> 6, lane = tid & 63;
  int b0 = blk * 2;
  int id0 = (t == 0) ? 0 : targets[b0 * T + t - 1];
  int id1 = (t == 0) ? 0 : targets[(b0 + 1) * T + t - 1];
  for (int i = tid; i < 1024; i += 512)
    h_s[i >> 9][i & 511] = h_prev[(size_t)(b0 + (i >> 9)) * 512 + (i & 511)];
  __syncthreads();

  // --- z partials: split-K x4, float4 weight loads ---
  {
    int nq = tid & 127, ks = tid >> 7;
    int n0 = nq * 4;
    const float* wb = WaT_h + (size_t)(ks * 128) * 512 + n0;
    float a00 = 0.f, a01 = 0.f, a02 = 0.f, a03 = 0.f;
    float a10 = 0.f, a11 = 0.f, a12 = 0.f, a13 = 0.f;
#pragma unroll 4
    for (int k = 0; k < 128; k++) {
      float4 w = *(const float4*)(wb + (size_t)k * 512);
      float hv0 = h_s[0][ks * 128 + k];
      float hv1 = h_s[1][ks * 128 + k];
      a00 += hv0 * w.x; a01 += hv0 * w.y; a02 += hv0 * w.z; a03 += hv0 * w.w;
      a10 += hv1 * w.x; a11 += hv1 * w.y; a12 += hv1 * w.z; a13 += hv1 * w.w;
    }
    *(float4*)&zred[ks][0][n0] = make_float4(a00, a01, a02, a03);
    *(float4*)&zred[ks][1][n0] = make_float4(a10, a11, a12, a13);
  }
  __syncthreads();

  // --- reduce + softmax over hid ---
  {
    int r = tid >> 8;
    int nn = tid & 255;
    int idr = r ? id1 : id0;
    float zv0 = Za[(size_t)idr * 512 + nn]
              + zred[0][r][nn] + zred[1][r][nn] + zred[2][r][nn] + zred[3][r][nn];
    float zv1 = Za[(size_t)idr * 512 + nn + 256]
              + zred[0][r][nn + 256] + zred[1][r][nn + 256] + zred[2][r][nn + 256] + zred[3][r][nn + 256];
    float m = fmaxf(zv0, zv1);
#pragma unroll
    for (int off = 32; off; off >>= 1) m = fmaxf(m, __shfl_xor(m, off, 64));
    if (lane == 0) redm[wid] = m;
    __syncthreads();
    float M = fmaxf(fmaxf(redm[r * 4], redm[r * 4 + 1]), fmaxf(redm[r * 4 + 2], redm[r * 4 + 3]));
    float e0 = expf(zv0 - M), e1 = expf(zv1 - M);
    float s = e0 + e1;
#pragma unroll
    for (int off = 32; off; off >>= 1) s += __shfl_xor(s, off, 64);
    if (lane == 0) reds[wid] = s;
    __syncthreads();
    float S = reds[r * 4] + reds[r * 4 + 1] + reds[r * 4 + 2] + reds[r * 4 + 3];
    float inv = 1.f / S;
    z_s[r][nn] = e0 * inv;
    z_s[r][nn + 256] = e1 * inv;
  }
  __syncthreads();

  // --- scores: 128 tasks (r,p), 16 per wave ---
#pragma unroll 1
  for (int q = 0; q < 16; q++) {
    int task = wid * 16 + q;
    int r = task >> 6, p = task & 63;
    const float4* fp = (const float4*)(feats + ((size_t)(b0 + r) * PPOS + p) * 512);
    const float4* ap = (const float4*)(z_s[r]);
    float4 f1 = fp[lane], a1 = ap[lane];
    float4 f2 = fp[lane + 64], a2 = ap[lane + 64];
    float d = f1.x * a1.x + f1.y * a1.y + f1.z * a1.z + f1.w * a1.w
            + f2.x * a2.x + f2.y * a2.y + f2.z * a2.z + f2.w * a2.w;
#pragma unroll
    for (int off = 32; off; off >>= 1) d += __shfl_xor(d, off, 64);
    if (lane == 0) sc_s[r][p] = d;
  }
  __syncthreads();

  // --- softmax over P=64 ---
  if (tid < 128) {
    int r = wid;
    float v = sc_s[r][lane];
    float m = v;
#pragma unroll
    for (int off = 32; off; off >>= 1) m = fmaxf(m, __shfl_xor(m, off, 64));
    float e = expf(v - m);
    float s = e;
#pragma unroll
    for (int off = 32; off; off >>= 1) s += __shfl_xor(s, off, 64);
    w_s[r][lane] = e / s;
  }
  __syncthreads();

  // --- ctx ---
#pragma unroll 1
  for (int r = 0; r < 2; r++) {
    const float* fb = feats + (size_t)(b0 + r) * PPOS * 512 + tid;
    float acc = 0.f;
#pragma unroll 8
    for (int p = 0; p < 64; p++) acc += w_s[r][p] * fb[(size_t)p * 512];
    ctx[(size_t)(b0 + r) * 512 + tid] = acc;
  }
}

// gates: 64x64 tile per block, 512 threads (8 waves, wave tile 16x32), split-bf16 MFMA + LSTM epilogue.
// blk in [0,256): rt = (blk>>3)&7, ct = (blk&7)*4 + (blk>>6)  (XCD-local col tiles)
__device__ void gates_body(char* smem, int blk, int t, int T,
                           const int* __restrict__ targets, const float* __restrict__ ctx,
                           const float* __restrict__ h_prev,
                           const short* __restrict__ BTgh, const short* __restrict__ BTgl,
                           const float* __restrict__ Gemb_p,
                           float* __restrict__ cbuf, float* __restrict__ h_new) {
  typedef short (*SB)[64][40];
  SB Ah = (SB)(smem);             // 10240
  SB Al = (SB)(smem + 10240);     // 10240
  SB Bh = (SB)(smem + 20480);     // 10240
  SB Bl = (SB)(smem + 30720);     // 10240
  float (*Cs)[68] = (float(*)[68])(smem + 40960);  // 17408
  int tid = threadIdx.x;
  int lane = tid & 63, wave = tid >> 6;
  int wm = (wave & 3) * 16, wn = (wave >> 2) * 32;
  int r15 = lane & 15, q4 = (lane >> 4) * 4, q8 = (lane >> 4) * 8;
  int rt = (blk >> 3) & 7, ct = (blk & 7) * 4 + (blk >> 6);
  int row0 = rt * 64, col0 = ct * 64;
  int smA = tid >> 3, skA = (tid & 7) * 4;   // 64 rows x 32k, float4 / bfv4 per thread
  const float* actx = ctx + (size_t)(row0 + smA) * 512;
  const float* ahst = h_prev + (size_t)(row0 + smA) * 512;
  const short* Bhp = BTgh + (size_t)(col0 + smA) * 1024 + skA;
  const short* Blp = BTgl + (size_t)(col0 + smA) * 1024 + skA;
  float4 a = *(const float4*)(actx + skA);
  bfv4 bh = *(const bfv4*)Bhp, bl = *(const bfv4*)Blp;
  f4 acc[2] = {};
  for (int kt = 0; kt < 32; kt++) {
    int buf = kt & 1;
    {
      float av[4] = {a.x, a.y, a.z, a.w};
      bfv4 ahv, alv;
#pragma unroll
      for (int i = 0; i < 4; i++) {
        short h = f2bf(av[i]);
        ahv[i] = h;
        alv[i] = f2bf(av[i] - bf2f(h));
      }
      *(bfv4*)&Ah[buf][smA][skA] = ahv;
      *(bfv4*)&Al[buf][smA][skA] = alv;
      *(bfv4*)&Bh[buf][smA][skA] = bh;
      *(bfv4*)&Bl[buf][smA][skA] = bl;
    }
    if (kt + 1 < 32) {
      int kk = (kt + 1) * 32 + skA;
      const float* s = (kk < 512) ? (actx + kk) : (ahst + kk - 512);
      a = *(const float4*)s;
      Bhp += 32; Blp += 32;
      bh = *(const bfv4*)Bhp; bl = *(const bfv4*)Blp;
    }
    __syncthreads();
    bf8 fah = *(const bf8*)&Ah[buf][wm + r15][q8];
    bf8 fal = *(const bf8*)&Al[buf][wm + r15][q8];
#pragma unroll
    for (int c = 0; c < 2; c++) {
      bf8 fbh = *(const bf8*)&Bh[buf][wn + c * 16 + r15][q8];
      bf8 fbl = *(const bf8*)&Bl[buf][wn + c * 16 + r15][q8];
      acc[c] = __builtin_amdgcn_mfma_f32_16x16x32_bf16(fah, fbh, acc[c], 0, 0, 0);
      acc[c] = __builtin_amdgcn_mfma_f32_16x16x32_bf16(fal, fbh, acc[c], 0, 0, 0);
      acc[c] = __builtin_amdgcn_mfma_f32_16x16x32_bf16(fah, fbl, acc[c], 0, 0, 0);
    }
  }
  __syncthreads();
#pragma unroll
  for (int c = 0; c < 2; c++)
#pragma unroll
    for (int i = 0; i < 4; i++)
      Cs[wm + q4 + i][wn + c * 16 + r15] = acc[c][i];
  __syncthreads();
#pragma unroll
  for (int e = 0; e < 2; e++) {
    int idx = e * 512 + tid;
    int row = idx >> 4, jj = idx & 15;
    int b = row0 + row;
    int jg = ct * 16 + jj;
    int id = (t == 0) ? 0 : targets[b * T + t - 1];
    float4 g4 = *(const float4*)(Gemb_p + (size_t)id * 2048 + col0 + jj * 4);
    float ig = sigmoidf_(Cs[row][jj * 4 + 0] + g4.x);
    float fg = sigmoidf_(Cs[row][jj * 4 + 1] + g4.y);
    float gg = tanhf(Cs[row][jj * 4 + 2] + g4.z);
    float og = sigmoidf_(Cs[row][jj * 4 + 3] + g4.w);
    float cn = fg * cbuf[(size_t)b * 512 + jg] + ig * gg;
    float hn = og * tanhf(cn);
    cbuf[(size_t)b * 512 + jg] = cn;
    h_new[(size_t)b * 512 + jg] = hn;
  }
}

// ---- cooperative all-steps kernel: 256 blocks x 512 threads, 2 grid.syncs per step ----
__global__ __launch_bounds__(512, 2) void steps_coop_k(
    const float* __restrict__ h0, float* __restrict__ h_hist, float* __restrict__ cbuf,
    float* __restrict__ ctxb, const int* __restrict__ targets, int T,
    const float* __restrict__ WaT_h, const float* __restrict__ Za, const float* __restrict__ feats,
    const short* __restrict__ BTgh, const short* __restrict__ BTgl, const float* __restrict__ Gemb_p) {
  cg::grid_group grid = cg::this_grid();
  __shared__ __align__(16) char smem[58368];
  int blk = blockIdx.x;
  for (int t = 0; t < T; t++) {
    const float* h_prev = (t == 0) ? h0 : (h_hist + (size_t)(t - 1) * BATCH * HIDC);
    float* h_new = h_hist + (size_t)t * BATCH * HIDC;
    attn_body(smem, blk, t, T, targets, WaT_h, Za, feats, h_prev, ctxb);
    grid.sync();
    gates_body(smem, blk, t, T, targets, ctxb, h_prev, BTgh, BTgl, Gemb_p, cbuf, h_new);
    grid.sync();
  }
}

// ---- fallback per-step kernels (same bodies) ----
__global__ __launch_bounds__(512) void attn_step_k(const float* __restrict__ h_prev,
                                                   const int* __restrict__ targets, int t, int T,
                                                   const float* __restrict__ WaT_h, const float* __restrict__ Za,
                                                   const float* __restrict__ feats, float* __restrict__ ctx) {
  __shared__ __align__(16) char smem[25664];
  attn_body(smem, blockIdx.x, t, T, targets, WaT_h, Za, feats, h_prev, ctx);
}

__global__ __launch_bounds__(512) void gates_step_k(const float* __restrict__ ctx, const float* __restrict__ h_prev,
                                                    const int* __restrict__ targets, int t, int T,
                                                    const short* __restrict__ BTgh, const short* __restrict__ BTgl,
                                                    const float* __restrict__ Gemb_p,
                                                    float* __restrict__ cbuf, float* __restrict__ h_new) {
  __shared__ __align__(16) char smem[58368];
  gates_body(smem, blockIdx.x, t, T, targets, ctx, h_prev, BTgh, BTgl, Gemb_p, cbuf, h_new);
}

// ---------------- final output GEMM over all timesteps ----------------
__global__ __launch_bounds__(256) void out_gemm_k(const float* __restrict__ h_hist, const float* __restrict__ WoT,
                                                  const float* __restrict__ bo, float* __restrict__ out, int T) {
  __shared__ float As[16][68];
  __shared__ float Bs[16][96];
  int tid = threadIdx.x;
  int tx = tid & 15, ty = tid >> 4;
  int row0 = blockIdx.x * 64;
  float acc[4][6] = {};
  for (int k0 = 0; k0 < 512; k0 += 16) {
    {
      int r = tid >> 2;
      int kk = (tid & 3) * 4;
      float4 v = *(const float4*)(h_hist + (size_t)(row0 + r) * 512 + k0 + kk);
      As[kk + 0][r] = v.x; As[kk + 1][r] = v.y; As[kk + 2][r] = v.z; As[kk + 3][r] = v.w;
    }
#pragma unroll
    for (int i = 0; i < 6; i++) {
      int e = tid + 256 * i;
      int kb = e / 96, n = e - kb * 96;
      Bs[kb][n] = WoT[(size_t)(k0 + kb) * 96 + n];
    }
    __syncthreads();
#pragma unroll
    for (int q = 0; q < 16; q++) {
      float av[4], bvv[6];
#pragma unroll
      for (int i = 0; i < 4; i++) av[i] = As[q][ty * 4 + i];
#pragma unroll
      for (int j = 0; j < 6; j++) bvv[j] = Bs[q][tx * 6 + j];
#pragma unroll
      for (int i = 0; i < 4; i++)
#pragma unroll
        for (int j = 0; j < 6; j++) acc[i][j] += av[i] * bvv[j];
    }
    __syncthreads();
  }
#pragma unroll
  for (int i = 0; i < 4; i++)
#pragma unroll
    for (int j = 0; j < 6; j++) {
      int row = row0 + ty * 4 + i;
      int tt = row >> 9, bb = row & 511;
      int cc = tx * 6 + j;
      out[((size_t)bb * T + tt) * 96 + cc] = acc[i][j] + bo[cc];
    }
}

extern "C" void kernel_launch(void* const* d_in, const int* in_sizes, int n_in,
                              void* d_out, int out_size, void* d_ws, size_t ws_size,
                              hipStream_t stream) {
  const float* features  = (const float*)d_in[0];
  const int*   targets   = (const int*)d_in[1];
  const float* Wfc       = (const float*)d_in[3];
  const float* bfc       = (const float*)d_in[4];
  const float* emb_table = (const float*)d_in[5];
  const float* Wa        = (const float*)d_in[6];
  const float* ba        = (const float*)d_in[7];
  const float* Wc        = (const float*)d_in[8];
  const float* bc        = (const float*)d_in[9];
  const float* Wih       = (const float*)d_in[10];
  const float* Whh       = (const float*)d_in[11];
  const float* bih       = (const float*)d_in[12];
  const float* bhh       = (const float*)d_in[13];
  const float* Wo        = (const float*)d_in[14];
  const float* bo        = (const float*)d_in[15];
  float* out = (float*)d_out;
  int T = in_sizes[1] / BATCH;  // 30

  char* base = (char*)d_ws;
  auto alloc = [&](size_t bytes) -> char* {
    char* p = base;
    base += (bytes + 255) & ~(size_t)255;
    return p;
  };
  float* feats   = (float*)alloc((size_t)BATCH * PPOS * HIDC * 4);
  float* WaT_h   = (float*)alloc(512 * 512 * 4);
  float* WaT_emb = (float*)alloc(512 * 512 * 4);
  float* WcT     = (float*)alloc(1024 * 512 * 4);
  float* WihT    = (float*)alloc(512 * 2048 * 4);
  float* tmp     = (float*)alloc((size_t)1024 * 2048 * 4);
  short* BTg_hi  = (short*)alloc((size_t)2048 * 1024 * 2);
  short* BTg_lo  = (short*)alloc((size_t)2048 * 1024 * 2);
  short* Wfc_hi  = (short*)alloc(512 * 512 * 2);
  short* Wfc_lo  = (short*)alloc(512 * 512 * 2);
  float* Gemb_p  = (float*)alloc(96 * 2048 * 4);
  float* Za      = (float*)alloc(96 * 512 * 4);
  float* bfused  = (float*)alloc(2048 * 4);
  float* WoT     = (float*)alloc(512 * 96 * 4);
  float* h0      = (float*)alloc(BATCH * HIDC * 4);
  float* cbuf    = (float*)alloc(BATCH * HIDC * 4);
  float* ctx     = (float*)alloc(BATCH * HIDC * 4);
  float* h_hist  = (float*)alloc((size_t)T * BATCH * HIDC * 4);

  dim3 tb(32, 8);
  transpose_k<<<dim3(16, 16), tb, 0, stream>>>(Wa, WaT_h, 512, 512, 1024);
  transpose_k<<<dim3(16, 16), tb, 0, stream>>>(Wa + 512, WaT_emb, 512, 512, 1024);
  transpose_k<<<dim3(32, 16), tb, 0, stream>>>(Wc, WcT, 512, 1024, 1024);
  transpose_k<<<dim3(16, 64), tb, 0, stream>>>(Wih, WihT, 2048, 512, 512);
  transpose_k<<<dim3(16, 3),  tb, 0, stream>>>(Wo, WoT, 96, 512, 512);

  // tmp = WcT[1024x512] @ WihT[512x2048]  ( = (Wih@Wc)^T )
  gemm64_k<false><<<dim3(32, 16), 256, 0, stream>>>(WcT, WihT, nullptr, tmp, 1024, 2048, 512);
  bfuse_k<<<8, 256, 0, stream>>>(Wih, bc, bih, bhh, bfused);
  build_btg_k<<<(2048 * 1024) / 256, 256, 0, stream>>>(tmp, Whh, BTg_hi, BTg_lo);
  gemb_k<<<dim3(8, 24), 256, 0, stream>>>(emb_table, tmp, bfused, Gemb_p);
  za_k<<<dim3(2, 24), 256, 0, stream>>>(emb_table, WaT_emb, ba, Za);
  split_k<<<(512 * 512) / 256, 256, 0, stream>>>(Wfc, Wfc_hi, Wfc_lo, 512 * 512);

  // feats = features @ Wfc.T + bfc   [32768 x 512], split-bf16 MFMA, XCD-swizzled grid
  feats_mfma_k<<<4096, 256, 0, stream>>>(features, Wfc_hi, Wfc_lo, bfc, feats);

  hipMemsetAsync(h0, 0, (size_t)BATCH * HIDC * 4, stream);
  hipMemsetAsync(cbuf, 0, (size_t)BATCH * HIDC * 4, stream);

  // cooperative all-steps kernel; host-visible launch validation with per-step fallback
  {
    const float* h0c = h0;
    void* args[] = {(void*)&h0c, (void*)&h_hist, (void*)&cbuf, (void*)&ctx,
                    (void*)&targets, (void*)&T, (void*)&WaT_h, (void*)&Za, (void*)&feats,
                    (void*)&BTg_hi, (void*)&BTg_lo, (void*)&Gemb_p};
    hipError_t cerr = hipLaunchCooperativeKernel((const void*)steps_coop_k,
                                                 dim3(256), dim3(512), args, 0, stream);
    if (cerr != hipSuccess) {
      (void)hipGetLastError();  // clear sticky error
      for (int t = 0; t < T; t++) {
        const float* h_prev = (t == 0) ? h0 : (h_hist + (size_t)(t - 1) * BATCH * HIDC);
        float* h_new = h_hist + (size_t)t * BATCH * HIDC;
        attn_step_k<<<256, 512, 0, stream>>>(h_prev, targets, t, T, WaT_h, Za, feats, ctx);
        gates_step_k<<<256, 512, 0, stream>>>(ctx, h_prev, targets, t, T, BTg_hi, BTg_lo, Gemb_p, cbuf, h_new);
      }
    }
  }

  out_gemm_k<<<(T * BATCH) / 64, 256, 0, stream>>>(h_hist, WoT, bo, out, T);
}

// Round 8
// 2014.648 us; speedup vs baseline: 1.8679x; 1.8679x over previous
//
#include <hip/hip_runtime.h>
#include <math.h>

// AttentionOCR: B=512, P=64, CIN=512, HID=512, EMB=512, NCLS=96, T=30
static constexpr int BATCH = 512;
static constexpr int PPOS  = 64;
static constexpr int HIDC  = 512;

typedef __attribute__((ext_vector_type(8))) short bf8;   // 8 bf16 = 4 VGPRs
typedef __attribute__((ext_vector_type(4))) short bfv4;  // 4 bf16 = 2 VGPRs
typedef __attribute__((ext_vector_type(4))) float f4;

static __device__ __forceinline__ float sigmoidf_(float x) { return 1.f / (1.f + expf(-x)); }

static __device__ __forceinline__ short f2bf(float x) {
  unsigned u = __float_as_uint(x);
  u = u + 0x7FFF + ((u >> 16) & 1);   // round-nearest-even to bf16
  return (short)(u >> 16);
}
static __device__ __forceinline__ float bf2f(short s) {
  return __uint_as_float(((unsigned)(unsigned short)s) << 16);
}

// ---------------- strided transpose: dst[C x R], dst[c][r] = src[r*ld + c] ----------------
__global__ void transpose_k(const float* __restrict__ src, float* __restrict__ dst, int R, int C, int ld) {
  __shared__ float tile[32][33];
  int c0 = blockIdx.x * 32, r0 = blockIdx.y * 32;
  int x = threadIdx.x;
  for (int yy = threadIdx.y; yy < 32; yy += 8) {
    int r = r0 + yy, c = c0 + x;
    if (r < R && c < C) tile[yy][x] = src[(size_t)r * ld + c];
  }
  __syncthreads();
  for (int yy = threadIdx.y; yy < 32; yy += 8) {
    int c = c0 + yy, r = r0 + x;
    if (r < R && c < C) dst[(size_t)c * R + r] = tile[x][yy];
  }
}

// ---- fp32 GEMM (setup only): C[MxN]=A[MxK]@B[KxN](+bias), dbuf, 1 barrier/tile ----
template <bool BIAS>
__global__ __launch_bounds__(256) void gemm64_k(const float* __restrict__ A, const float* __restrict__ Bm,
                                                const float* __restrict__ bias, float* __restrict__ C,
                                                int M, int N, int K) {
  __shared__ float As[2][16][68];
  __shared__ float Bs[2][16][64];
  int tid = threadIdx.x;
  int tx = tid & 15, ty = tid >> 4;
  int row0 = blockIdx.y * 64, col0 = blockIdx.x * 64;
  int ar = tid >> 2, ak = (tid & 3) * 4;
  int bkb = tid >> 4, bn = (tid & 15) * 4;
  const float* Aptr = A + (size_t)(row0 + ar) * K + ak;
  const float* Bptr = Bm + (size_t)bkb * N + col0 + bn;
  float4 av = *(const float4*)Aptr;
  float4 bv = *(const float4*)Bptr;
  float acc[4][4] = {};
  int NT = K / 16;
  for (int kt = 0; kt < NT; kt++) {
    int buf = kt & 1;
    As[buf][ak + 0][ar] = av.x; As[buf][ak + 1][ar] = av.y;
    As[buf][ak + 2][ar] = av.z; As[buf][ak + 3][ar] = av.w;
    *(float4*)&Bs[buf][bkb][bn] = bv;
    if (kt + 1 < NT) {
      Aptr += 16; Bptr += (size_t)16 * N;
      av = *(const float4*)Aptr;
      bv = *(const float4*)Bptr;
    }
    __syncthreads();
#pragma unroll
    for (int q = 0; q < 16; q++) {
      float4 a4 = *(const float4*)&As[buf][q][ty * 4];
      float4 b4 = *(const float4*)&Bs[buf][q][tx * 4];
      acc[0][0] += a4.x * b4.x; acc[0][1] += a4.x * b4.y; acc[0][2] += a4.x * b4.z; acc[0][3] += a4.x * b4.w;
      acc[1][0] += a4.y * b4.x; acc[1][1] += a4.y * b4.y; acc[1][2] += a4.y * b4.z; acc[1][3] += a4.y * b4.w;
      acc[2][0] += a4.z * b4.x; acc[2][1] += a4.z * b4.y; acc[2][2] += a4.z * b4.z; acc[2][3] += a4.z * b4.w;
      acc[3][0] += a4.w * b4.x; acc[3][1] += a4.w * b4.y; acc[3][2] += a4.w * b4.z; acc[3][3] += a4.w * b4.w;
    }
  }
#pragma unroll
  for (int i = 0; i < 4; i++)
#pragma unroll
    for (int j = 0; j < 4; j++) {
      int rr = row0 + ty * 4 + i, cc = col0 + tx * 4 + j;
      float v = acc[i][j];
      if (BIAS) v += bias[cc];
      C[(size_t)rr * N + cc] = v;
    }
}

// ---------------- bfused[n] = bih[n] + bhh[n] + dot(Wih[n,:], bc) ----------------
__global__ void bfuse_k(const float* __restrict__ Wih, const float* __restrict__ bc,
                        const float* __restrict__ bih, const float* __restrict__ bhh,
                        float* __restrict__ bf) {
  int n = blockIdx.x * 256 + threadIdx.x;  // < 2048
  float s = bih[n] + bhh[n];
  const float* w = Wih + (size_t)n * 512;
  for (int m = 0; m < 512; m++) s += w[m] * bc[m];
  bf[n] = s;
}

// ---- BTg[2048 cp][1024 k] bf16 hi/lo: BTg[cp][k] = Bcat[k][cp], cp = j*4+g gate-interleaved ----
__global__ void build_btg_k(const float* __restrict__ tmp, const float* __restrict__ Whh,
                            short* __restrict__ hi, short* __restrict__ lo) {
  int idx = blockIdx.x * 256 + threadIdx.x;  // < 2048*1024
  int cp = idx >> 10, k = idx & 1023;
  int j = cp >> 2, g = cp & 3;
  int n = g * 512 + j;
  float v = (k < 512) ? tmp[(size_t)(512 + k) * 2048 + n] : Whh[(size_t)n * 512 + (k - 512)];
  short h = f2bf(v);
  hi[idx] = h;
  lo[idx] = f2bf(v - bf2f(h));
}

// ---- split fp32 -> bf16 hi/lo ----
__global__ void split_k(const float* __restrict__ src, short* __restrict__ hi, short* __restrict__ lo, int n) {
  int i = blockIdx.x * 256 + threadIdx.x;
  if (i < n) {
    float x = src[i];
    short h = f2bf(x);
    hi[i] = h;
    lo[i] = f2bf(x - bf2f(h));
  }
}

// ---- split Wa's h-half (cols 0..511 of [512 x 1024]) to bf16 hi/lo row-major [n][k] ----
__global__ void split_wah_k(const float* __restrict__ Wa, short* __restrict__ hi, short* __restrict__ lo) {
  int idx = blockIdx.x * 256 + threadIdx.x;  // < 512*512
  int n = idx >> 9, k = idx & 511;
  float v = Wa[(size_t)n * 1024 + k];
  short h = f2bf(v);
  hi[idx] = h;
  lo[idx] = f2bf(v - bf2f(h));
}

// ---------------- Gemb_p[96 x 2048] = (emb_table @ tmp[0:512]) + bfused, columns permuted ----------------
__global__ __launch_bounds__(256) void gemb_k(const float* __restrict__ emb_table, const float* __restrict__ tmp,
                                              const float* __restrict__ bfused, float* __restrict__ Gemb_p) {
  __shared__ float emb_s[4][512];
  int tid = threadIdx.x;
  int n0 = blockIdx.x * 256;
  int e0 = blockIdx.y * 4;
  for (int i = tid; i < 2048; i += 256)
    emb_s[i >> 9][i & 511] = emb_table[(size_t)(e0 + (i >> 9)) * 512 + (i & 511)];
  __syncthreads();
  int n = n0 + tid;
  float acc[4] = {};
  for (int k = 0; k < 512; k++) {
    float w = tmp[(size_t)k * 2048 + n];
#pragma unroll
    for (int e = 0; e < 4; e++) acc[e] += emb_s[e][k] * w;
  }
  int cp = (n & 511) * 4 + (n >> 9);
  float b = bfused[n];
#pragma unroll
  for (int e = 0; e < 4; e++) Gemb_p[(size_t)(e0 + e) * 2048 + cp] = acc[e] + b;
}

// ---------------- Za[96 x 512] = emb_table @ WaT_emb + ba ----------------
__global__ __launch_bounds__(256) void za_k(const float* __restrict__ emb_table, const float* __restrict__ WaT_emb,
                                            const float* __restrict__ ba, float* __restrict__ Za) {
  __shared__ float emb_s[4][512];
  int tid = threadIdx.x;
  int n0 = blockIdx.x * 256;
  int e0 = blockIdx.y * 4;
  for (int i = tid; i < 2048; i += 256)
    emb_s[i >> 9][i & 511] = emb_table[(size_t)(e0 + (i >> 9)) * 512 + (i & 511)];
  __syncthreads();
  int n = n0 + tid;
  float acc[4] = {};
  for (int k = 0; k < 512; k++) {
    float w = WaT_emb[(size_t)k * 512 + n];
#pragma unroll
    for (int e = 0; e < 4; e++) acc[e] += emb_s[e][k] * w;
  }
  float b = ba[n];
#pragma unroll
  for (int e = 0; e < 4; e++) Za[(size_t)(e0 + e) * 512 + n] = acc[e] + b;
}

// ---- feats: C[32768x512] = features @ Wfc^T (+bfc). XCD/temporal-swizzled linear grid (4096). ----
__global__ __launch_bounds__(256) void feats_mfma_k(const float* __restrict__ A,
                                                    const short* __restrict__ BTh, const short* __restrict__ BTl,
                                                    const float* __restrict__ bias, float* __restrict__ C) {
  __shared__ short Ah[2][64][40], Al[2][64][40], Bh[2][64][40], Bl[2][64][40];
  int blk = blockIdx.x;
  int xt = (blk >> 3) & 7;
  int ytile = (blk >> 6) * 8 + (blk & 7);
  int row0 = ytile * 64, col0 = xt * 64;
  int tid = threadIdx.x;
  int lane = tid & 63, wave = tid >> 6;
  int wm = (wave & 1) * 32, wn = (wave >> 1) * 32;
  int r15 = lane & 15, q8 = (lane >> 4) * 8;
  int sm = tid >> 2, sk = (tid & 3) * 8;
  const float* Ap = A + (size_t)(row0 + sm) * 512 + sk;
  const short* Bhp = BTh + (size_t)(col0 + sm) * 512 + sk;
  const short* Blp = BTl + (size_t)(col0 + sm) * 512 + sk;
  float4 a0 = *(const float4*)Ap, a1 = *(const float4*)(Ap + 4);
  bf8 bh = *(const bf8*)Bhp, bl = *(const bf8*)Blp;
  f4 acc[2][2] = {};
  for (int kt = 0; kt < 16; kt++) {
    int buf = kt & 1;
    {
      float av[8] = {a0.x, a0.y, a0.z, a0.w, a1.x, a1.y, a1.z, a1.w};
      bf8 ahv, alv;
#pragma unroll
      for (int i = 0; i < 8; i++) {
        short h = f2bf(av[i]);
        ahv[i] = h;
        alv[i] = f2bf(av[i] - bf2f(h));
      }
      *(bf8*)&Ah[buf][sm][sk] = ahv;
      *(bf8*)&Al[buf][sm][sk] = alv;
      *(bf8*)&Bh[buf][sm][sk] = bh;
      *(bf8*)&Bl[buf][sm][sk] = bl;
    }
    if (kt + 1 < 16) {
      Ap += 32; Bhp += 32; Blp += 32;
      a0 = *(const float4*)Ap; a1 = *(const float4*)(Ap + 4);
      bh = *(const bf8*)Bhp; bl = *(const bf8*)Blp;
    }
    __syncthreads();
    bf8 fah[2], fal[2], fbh[2], fbl[2];
#pragma unroll
    for (int r = 0; r < 2; r++) {
      fah[r] = *(const bf8*)&Ah[buf][wm + r * 16 + r15][q8];
      fal[r] = *(const bf8*)&Al[buf][wm + r * 16 + r15][q8];
    }
#pragma unroll
    for (int c = 0; c < 2; c++) {
      fbh[c] = *(const bf8*)&Bh[buf][wn + c * 16 + r15][q8];
      fbl[c] = *(const bf8*)&Bl[buf][wn + c * 16 + r15][q8];
    }
#pragma unroll
    for (int r = 0; r < 2; r++)
#pragma unroll
      for (int c = 0; c < 2; c++) {
        acc[r][c] = __builtin_amdgcn_mfma_f32_16x16x32_bf16(fah[r], fbh[c], acc[r][c], 0, 0, 0);
        acc[r][c] = __builtin_amdgcn_mfma_f32_16x16x32_bf16(fal[r], fbh[c], acc[r][c], 0, 0, 0);
        acc[r][c] = __builtin_amdgcn_mfma_f32_16x16x32_bf16(fah[r], fbl[c], acc[r][c], 0, 0, 0);
      }
  }
#pragma unroll
  for (int r = 0; r < 2; r++)
#pragma unroll
    for (int c = 0; c < 2; c++) {
      int col = col0 + wn + c * 16 + r15;
      float bv = bias[col];
#pragma unroll
      for (int i = 0; i < 4; i++) {
        int row = row0 + wm + r * 16 + (lane >> 4) * 4 + i;
        C[(size_t)row * 512 + col] = acc[r][c][i] + bv;
      }
    }
}

// ---- per-step z GEMM: zbuf[512x512] = h_prev @ WaH^T, split-bf16 MFMA ----
// grid (8,16), 256 thr, tile 32x64 (clone of R5-validated gates staging, K=512).
__global__ __launch_bounds__(256) void z_mfma_k(const float* __restrict__ h_prev,
                                                const short* __restrict__ BTh, const short* __restrict__ BTl,
                                                float* __restrict__ zbuf) {
  __shared__ short Ah[2][32][40], Al[2][32][40], Bh[2][64][40], Bl[2][64][40];
  int tid = threadIdx.x;
  int lane = tid & 63, wave = tid >> 6;
  int wm = (wave & 1) * 16, wn = (wave >> 1) * 32;
  int r15 = lane & 15, q4 = (lane >> 4) * 4, q8 = (lane >> 4) * 8;
  int row0 = blockIdx.y * 32, col0 = blockIdx.x * 64;
  int smA = tid >> 3, skA = (tid & 7) * 4;
  int smB = tid >> 2, skB = (tid & 3) * 8;
  const float* arow = h_prev + (size_t)(row0 + smA) * 512;
  const short* Bhp = BTh + (size_t)(col0 + smB) * 512 + skB;
  const short* Blp = BTl + (size_t)(col0 + smB) * 512 + skB;
  float4 a = *(const float4*)(arow + skA);
  bf8 bh = *(const bf8*)Bhp, bl = *(const bf8*)Blp;
  f4 acc[2] = {};
  for (int kt = 0; kt < 16; kt++) {
    int buf = kt & 1;
    {
      float av[4] = {a.x, a.y, a.z, a.w};
      bfv4 ahv, alv;
#pragma unroll
      for (int i = 0; i < 4; i++) {
        short h = f2bf(av[i]);
        ahv[i] = h;
        alv[i] = f2bf(av[i] - bf2f(h));
      }
      *(bfv4*)&Ah[buf][smA][skA] = ahv;
      *(bfv4*)&Al[buf][smA][skA] = alv;
      *(bf8*)&Bh[buf][smB][skB] = bh;
      *(bf8*)&Bl[buf][smB][skB] = bl;
    }
    if (kt + 1 < 16) {
      a = *(const float4*)(arow + (kt + 1) * 32 + skA);
      Bhp += 32; Blp += 32;
      bh = *(const bf8*)Bhp; bl = *(const bf8*)Blp;
    }
    __syncthreads();
    bf8 fah = *(const bf8*)&Ah[buf][wm + r15][q8];
    bf8 fal = *(const bf8*)&Al[buf][wm + r15][q8];
#pragma unroll
    for (int c = 0; c < 2; c++) {
      bf8 fbh = *(const bf8*)&Bh[buf][wn + c * 16 + r15][q8];
      bf8 fbl = *(const bf8*)&Bl[buf][wn + c * 16 + r15][q8];
      acc[c] = __builtin_amdgcn_mfma_f32_16x16x32_bf16(fah, fbh, acc[c], 0, 0, 0);
      acc[c] = __builtin_amdgcn_mfma_f32_16x16x32_bf16(fal, fbh, acc[c], 0, 0, 0);
      acc[c] = __builtin_amdgcn_mfma_f32_16x16x32_bf16(fah, fbl, acc[c], 0, 0, 0);
    }
  }
#pragma unroll
  for (int c = 0; c < 2; c++) {
    int col = col0 + wn + c * 16 + r15;
#pragma unroll
    for (int i = 0; i < 4; i++)
      zbuf[(size_t)(row0 + wm + q4 + i) * 512 + col] = acc[c][i];
  }
}

// ---- attn finish: softmax(z+Za[id]) -> scores -> softmax(P) -> ctx. 2 rows/block, 256 blocks, 512 thr. ----
__global__ __launch_bounds__(512) void attn_fin_k(const float* __restrict__ zbuf,
                                                  const int* __restrict__ targets, int t, int T,
                                                  const float* __restrict__ Za, const float* __restrict__ feats,
                                                  float* __restrict__ ctx) {
  __shared__ __align__(16) float z_s[2][512];
  __shared__ float redm[8], reds[8];
  __shared__ float sc_s[2][64];
  __shared__ float w_s[2][64];
  int tid = threadIdx.x;
  int wid = tid >> 6, lane = tid & 63;
  int b0 = blockIdx.x * 2;
  int id0 = (t == 0) ? 0 : targets[b0 * T + t - 1];
  int id1 = (t == 0) ? 0 : targets[(b0 + 1) * T + t - 1];

  // --- softmax over hid (row r = tid>>8, 4 waves/row, 2 cols each) ---
  {
    int r = tid >> 8;
    int nn = tid & 255;
    int idr = r ? id1 : id0;
    const float* zrow = zbuf + (size_t)(b0 + r) * 512;
    const float* za = Za + (size_t)idr * 512;
    float zv0 = zrow[nn] + za[nn];
    float zv1 = zrow[nn + 256] + za[nn + 256];
    float m = fmaxf(zv0, zv1);
#pragma unroll
    for (int off = 32; off; off >>= 1) m = fmaxf(m, __shfl_xor(m, off, 64));
    if (lane == 0) redm[wid] = m;
    __syncthreads();
    float M = fmaxf(fmaxf(redm[r * 4], redm[r * 4 + 1]), fmaxf(redm[r * 4 + 2], redm[r * 4 + 3]));
    float e0 = expf(zv0 - M), e1 = expf(zv1 - M);
    float s = e0 + e1;
#pragma unroll
    for (int off = 32; off; off >>= 1) s += __shfl_xor(s, off, 64);
    if (lane == 0) reds[wid] = s;
    __syncthreads();
    float S = reds[r * 4] + reds[r * 4 + 1] + reds[r * 4 + 2] + reds[r * 4 + 3];
    float inv = 1.f / S;
    z_s[r][nn] = e0 * inv;
    z_s[r][nn + 256] = e1 * inv;
  }
  __syncthreads();

  // --- scores: 128 tasks (r,p), 16 per wave ---
#pragma unroll 1
  for (int q = 0; q < 16; q++) {
    int task = wid * 16 + q;
    int r = task >> 6, p = task & 63;
    const float4* fp = (const float4*)(feats + ((size_t)(b0 + r) * PPOS + p) * 512);
    const float4* ap = (const float4*)(z_s[r]);
    float4 f1 = fp[lane], a1 = ap[lane];
    float4 f2 = fp[lane + 64], a2 = ap[lane + 64];
    float d = f1.x * a1.x + f1.y * a1.y + f1.z * a1.z + f1.w * a1.w
            + f2.x * a2.x + f2.y * a2.y + f2.z * a2.z + f2.w * a2.w;
#pragma unroll
    for (int off = 32; off; off >>= 1) d += __shfl_xor(d, off, 64);
    if (lane == 0) sc_s[r][p] = d;
  }
  __syncthreads();

  // --- softmax over P=64 ---
  if (tid < 128) {
    int r = wid;
    float v = sc_s[r][lane];
    float m = v;
#pragma unroll
    for (int off = 32; off; off >>= 1) m = fmaxf(m, __shfl_xor(m, off, 64));
    float e = expf(v - m);
    float s = e;
#pragma unroll
    for (int off = 32; off; off >>= 1) s += __shfl_xor(s, off, 64);
    w_s[r][lane] = e / s;
  }
  __syncthreads();

  // --- ctx ---
#pragma unroll 1
  for (int r = 0; r < 2; r++) {
    const float* fb = feats + (size_t)(b0 + r) * PPOS * 512 + tid;
    float acc = 0.f;
#pragma unroll 8
    for (int p = 0; p < 64; p++) acc += w_s[r][p] * fb[(size_t)p * 512];
    ctx[(size_t)(b0 + r) * 512 + tid] = acc;
  }
}

// ---- gates: R4-validated. [ctx|h][512x1024] @ Bcat (+Gemb[id]) -> LSTM. grid (32,8), 256 thr, 64x64. ----
__global__ __launch_bounds__(256) void gates_mfma_k(const float* __restrict__ ctx, const float* __restrict__ h_prev,
                                                    const int* __restrict__ targets, int t, int T,
                                                    const short* __restrict__ BTh, const short* __restrict__ BTl,
                                                    const float* __restrict__ Gemb_p,
                                                    float* __restrict__ cbuf, float* __restrict__ h_new) {
  __shared__ short Ah[2][64][40], Al[2][64][40], Bh[2][64][40], Bl[2][64][40];
  __shared__ float Cs[64][68];
  int tid = threadIdx.x;
  int lane = tid & 63, wave = tid >> 6;
  int wm = (wave & 1) * 32, wn = (wave >> 1) * 32;
  int r15 = lane & 15, q8 = (lane >> 4) * 8;
  int row0 = blockIdx.y * 64, col0 = blockIdx.x * 64;
  int sm = tid >> 2, sk = (tid & 3) * 8;
  const float* actx = ctx + (size_t)(row0 + sm) * 512;
  const float* ahst = h_prev + (size_t)(row0 + sm) * 512;
  const short* Bhp = BTh + (size_t)(col0 + sm) * 1024 + sk;
  const short* Blp = BTl + (size_t)(col0 + sm) * 1024 + sk;
  float4 a0 = *(const float4*)(actx + sk), a1 = *(const float4*)(actx + sk + 4);
  bf8 bh = *(const bf8*)Bhp, bl = *(const bf8*)Blp;
  f4 acc[2][2] = {};
  for (int kt = 0; kt < 32; kt++) {
    int buf = kt & 1;
    {
      float av[8] = {a0.x, a0.y, a0.z, a0.w, a1.x, a1.y, a1.z, a1.w};
      bf8 ahv, alv;
#pragma unroll
      for (int i = 0; i < 8; i++) {
        short h = f2bf(av[i]);
        ahv[i] = h;
        alv[i] = f2bf(av[i] - bf2f(h));
      }
      *(bf8*)&Ah[buf][sm][sk] = ahv;
      *(bf8*)&Al[buf][sm][sk] = alv;
      *(bf8*)&Bh[buf][sm][sk] = bh;
      *(bf8*)&Bl[buf][sm][sk] = bl;
    }
    if (kt + 1 < 32) {
      int kk = (kt + 1) * 32 + sk;
      const float* s = (kk < 512) ? (actx + kk) : (ahst + kk - 512);
      a0 = *(const float4*)s; a1 = *(const float4*)(s + 4);
      Bhp += 32; Blp += 32;
      bh = *(const bf8*)Bhp; bl = *(const bf8*)Blp;
    }
    __syncthreads();
    bf8 fah[2], fal[2], fbh[2], fbl[2];
#pragma unroll
    for (int r = 0; r < 2; r++) {
      fah[r] = *(const bf8*)&Ah[buf][wm + r * 16 + r15][q8];
      fal[r] = *(const bf8*)&Al[buf][wm + r * 16 + r15][q8];
    }
#pragma unroll
    for (int c = 0; c < 2; c++) {
      fbh[c] = *(const bf8*)&Bh[buf][wn + c * 16 + r15][q8];
      fbl[c] = *(const bf8*)&Bl[buf][wn + c * 16 + r15][q8];
    }
#pragma unroll
    for (int r = 0; r < 2; r++)
#pragma unroll
      for (int c = 0; c < 2; c++) {
        acc[r][c] = __builtin_amdgcn_mfma_f32_16x16x32_bf16(fah[r], fbh[c], acc[r][c], 0, 0, 0);
        acc[r][c] = __builtin_amdgcn_mfma_f32_16x16x32_bf16(fal[r], fbh[c], acc[r][c], 0, 0, 0);
        acc[r][c] = __builtin_amdgcn_mfma_f32_16x16x32_bf16(fah[r], fbl[c], acc[r][c], 0, 0, 0);
      }
  }
  // stage C tile to LDS (MFMA C layout -> row/col), then LSTM epilogue
#pragma unroll
  for (int r = 0; r < 2; r++)
#pragma unroll
    for (int c = 0; c < 2; c++)
#pragma unroll
      for (int i = 0; i < 4; i++)
        Cs[wm + r * 16 + (lane >> 4) * 4 + i][wn + c * 16 + r15] = acc[r][c][i];
  __syncthreads();
#pragma unroll
  for (int i = 0; i < 4; i++) {
    int idx = i * 256 + tid;
    int row = idx >> 4, jj = idx & 15;
    int b = row0 + row;
    int jg = (col0 >> 2) + jj;
    int id = (t == 0) ? 0 : targets[b * T + t - 1];
    float4 g4 = *(const float4*)(Gemb_p + (size_t)id * 2048 + col0 + jj * 4);
    float ig = sigmoidf_(Cs[row][jj * 4 + 0] + g4.x);
    float fg = sigmoidf_(Cs[row][jj * 4 + 1] + g4.y);
    float gg = tanhf(Cs[row][jj * 4 + 2] + g4.z);
    float og = sigmoidf_(Cs[row][jj * 4 + 3] + g4.w);
    float cn = fg * cbuf[(size_t)b * 512 + jg] + ig * gg;
    float hn = og * tanhf(cn);
    cbuf[(size_t)b * 512 + jg] = cn;
    h_new[(size_t)b * 512 + jg] = hn;
  }
}

// ---------------- final output GEMM over all timesteps ----------------
__global__ __launch_bounds__(256) void out_gemm_k(const float* __restrict__ h_hist, const float* __restrict__ WoT,
                                                  const float* __restrict__ bo, float* __restrict__ out, int T) {
  __shared__ float As[16][68];
  __shared__ float Bs[16][96];
  int tid = threadIdx.x;
  int tx = tid & 15, ty = tid >> 4;
  int row0 = blockIdx.x * 64;
  float acc[4][6] = {};
  for (int k0 = 0; k0 < 512; k0 += 16) {
    {
      int r = tid >> 2;
      int kk = (tid & 3) * 4;
      float4 v = *(const float4*)(h_hist + (size_t)(row0 + r) * 512 + k0 + kk);
      As[kk + 0][r] = v.x; As[kk + 1][r] = v.y; As[kk + 2][r] = v.z; As[kk + 3][r] = v.w;
    }
#pragma unroll
    for (int i = 0; i < 6; i++) {
      int e = tid + 256 * i;
      int kb = e / 96, n = e - kb * 96;
      Bs[kb][n] = WoT[(size_t)(k0 + kb) * 96 + n];
    }
    __syncthreads();
#pragma unroll
    for (int q = 0; q < 16; q++) {
      float av[4], bvv[6];
#pragma unroll
      for (int i = 0; i < 4; i++) av[i] = As[q][ty * 4 + i];
#pragma unroll
      for (int j = 0; j < 6; j++) bvv[j] = Bs[q][tx * 6 + j];
#pragma unroll
      for (int i = 0; i < 4; i++)
#pragma unroll
        for (int j = 0; j < 6; j++) acc[i][j] += av[i] * bvv[j];
    }
    __syncthreads();
  }
#pragma unroll
  for (int i = 0; i < 4; i++)
#pragma unroll
    for (int j = 0; j < 6; j++) {
      int row = row0 + ty * 4 + i;
      int tt = row >> 9, bb = row & 511;
      int cc = tx * 6 + j;
      out[((size_t)bb * T + tt) * 96 + cc] = acc[i][j] + bo[cc];
    }
}

extern "C" void kernel_launch(void* const* d_in, const int* in_sizes, int n_in,
                              void* d_out, int out_size, void* d_ws, size_t ws_size,
                              hipStream_t stream) {
  const float* features  = (const float*)d_in[0];
  const int*   targets   = (const int*)d_in[1];
  const float* Wfc       = (const float*)d_in[3];
  const float* bfc       = (const float*)d_in[4];
  const float* emb_table = (const float*)d_in[5];
  const float* Wa        = (const float*)d_in[6];
  const float* ba        = (const float*)d_in[7];
  const float* Wc        = (const float*)d_in[8];
  const float* bc        = (const float*)d_in[9];
  const float* Wih       = (const float*)d_in[10];
  const float* Whh       = (const float*)d_in[11];
  const float* bih       = (const float*)d_in[12];
  const float* bhh       = (const float*)d_in[13];
  const float* Wo        = (const float*)d_in[14];
  const float* bo        = (const float*)d_in[15];
  float* out = (float*)d_out;
  int T = in_sizes[1] / BATCH;  // 30

  char* base = (char*)d_ws;
  auto alloc = [&](size_t bytes) -> char* {
    char* p = base;
    base += (bytes + 255) & ~(size_t)255;
    return p;
  };
  float* feats   = (float*)alloc((size_t)BATCH * PPOS * HIDC * 4);
  float* WaT_emb = (float*)alloc(512 * 512 * 4);
  float* WcT     = (float*)alloc(1024 * 512 * 4);
  float* WihT    = (float*)alloc(512 * 2048 * 4);
  float* tmp     = (float*)alloc((size_t)1024 * 2048 * 4);
  short* BTg_hi  = (short*)alloc((size_t)2048 * 1024 * 2);
  short* BTg_lo  = (short*)alloc((size_t)2048 * 1024 * 2);
  short* Wfc_hi  = (short*)alloc(512 * 512 * 2);
  short* Wfc_lo  = (short*)alloc(512 * 512 * 2);
  short* WaH_hi  = (short*)alloc(512 * 512 * 2);
  short* WaH_lo  = (short*)alloc(512 * 512 * 2);
  float* Gemb_p  = (float*)alloc(96 * 2048 * 4);
  float* Za      = (float*)alloc(96 * 512 * 4);
  float* bfused  = (float*)alloc(2048 * 4);
  float* WoT     = (float*)alloc(512 * 96 * 4);
  float* h0      = (float*)alloc(BATCH * HIDC * 4);
  float* cbuf    = (float*)alloc(BATCH * HIDC * 4);
  float* ctx     = (float*)alloc(BATCH * HIDC * 4);
  float* zbuf    = (float*)alloc(BATCH * HIDC * 4);
  float* h_hist  = (float*)alloc((size_t)T * BATCH * HIDC * 4);

  dim3 tb(32, 8);
  transpose_k<<<dim3(16, 16), tb, 0, stream>>>(Wa + 512, WaT_emb, 512, 512, 1024);
  transpose_k<<<dim3(32, 16), tb, 0, stream>>>(Wc, WcT, 512, 1024, 1024);
  transpose_k<<<dim3(16, 64), tb, 0, stream>>>(Wih, WihT, 2048, 512, 512);
  transpose_k<<<dim3(16, 3),  tb, 0, stream>>>(Wo, WoT, 96, 512, 512);

  // tmp = WcT[1024x512] @ WihT[512x2048]  ( = (Wih@Wc)^T )
  gemm64_k<false><<<dim3(32, 16), 256, 0, stream>>>(WcT, WihT, nullptr, tmp, 1024, 2048, 512);
  bfuse_k<<<8, 256, 0, stream>>>(Wih, bc, bih, bhh, bfused);
  build_btg_k<<<(2048 * 1024) / 256, 256, 0, stream>>>(tmp, Whh, BTg_hi, BTg_lo);
  gemb_k<<<dim3(8, 24), 256, 0, stream>>>(emb_table, tmp, bfused, Gemb_p);
  za_k<<<dim3(2, 24), 256, 0, stream>>>(emb_table, WaT_emb, ba, Za);
  split_k<<<(512 * 512) / 256, 256, 0, stream>>>(Wfc, Wfc_hi, Wfc_lo, 512 * 512);
  split_wah_k<<<(512 * 512) / 256, 256, 0, stream>>>(Wa, WaH_hi, WaH_lo);

  // feats = features @ Wfc.T + bfc   [32768 x 512], split-bf16 MFMA, XCD-swizzled grid
  feats_mfma_k<<<4096, 256, 0, stream>>>(features, Wfc_hi, Wfc_lo, bfc, feats);

  hipMemsetAsync(h0, 0, (size_t)BATCH * HIDC * 4, stream);
  hipMemsetAsync(cbuf, 0, (size_t)BATCH * HIDC * 4, stream);

  for (int t = 0; t < T; t++) {
    const float* h_prev = (t == 0) ? h0 : (h_hist + (size_t)(t - 1) * BATCH * HIDC);
    float* h_new = h_hist + (size_t)t * BATCH * HIDC;
    z_mfma_k<<<dim3(8, 16), 256, 0, stream>>>(h_prev, WaH_hi, WaH_lo, zbuf);
    attn_fin_k<<<256, 512, 0, stream>>>(zbuf, targets, t, T, Za, feats, ctx);
    gates_mfma_k<<<dim3(32, 8), 256, 0, stream>>>(ctx, h_prev, targets, t, T, BTg_hi, BTg_lo, Gemb_p, cbuf, h_new);
  }
  out_gemm_k<<<(T * BATCH) / 64, 256, 0, stream>>>(h_hist, WoT, bo, out, T);
}

// Round 9
// 1948.348 us; speedup vs baseline: 1.9314x; 1.0340x over previous
//
#include <hip/hip_runtime.h>
#include <math.h>

// AttentionOCR: B=512, P=64, CIN=512, HID=512, EMB=512, NCLS=96, T=30
static constexpr int BATCH = 512;
static constexpr int PPOS  = 64;
static constexpr int HIDC  = 512;

typedef __attribute__((ext_vector_type(8))) short bf8;   // 8 bf16 = 4 VGPRs
typedef __attribute__((ext_vector_type(4))) short bfv4;  // 4 bf16 = 2 VGPRs
typedef __attribute__((ext_vector_type(4))) float f4;

static __device__ __forceinline__ float sigmoidf_(float x) { return 1.f / (1.f + expf(-x)); }

static __device__ __forceinline__ short f2bf(float x) {
  unsigned u = __float_as_uint(x);
  u = u + 0x7FFF + ((u >> 16) & 1);   // round-nearest-even to bf16
  return (short)(u >> 16);
}
static __device__ __forceinline__ float bf2f(short s) {
  return __uint_as_float(((unsigned)(unsigned short)s) << 16);
}

// ---------------- strided transpose: dst[C x R], dst[c][r] = src[r*ld + c] ----------------
__global__ void transpose_k(const float* __restrict__ src, float* __restrict__ dst, int R, int C, int ld) {
  __shared__ float tile[32][33];
  int c0 = blockIdx.x * 32, r0 = blockIdx.y * 32;
  int x = threadIdx.x;
  for (int yy = threadIdx.y; yy < 32; yy += 8) {
    int r = r0 + yy, c = c0 + x;
    if (r < R && c < C) tile[yy][x] = src[(size_t)r * ld + c];
  }
  __syncthreads();
  for (int yy = threadIdx.y; yy < 32; yy += 8) {
    int c = c0 + yy, r = r0 + x;
    if (r < R && c < C) dst[(size_t)c * R + r] = tile[x][yy];
  }
}

// ---- fp32 GEMM (setup only): C[MxN]=A[MxK]@B[KxN](+bias), dbuf, 1 barrier/tile ----
template <bool BIAS>
__global__ __launch_bounds__(256) void gemm64_k(const float* __restrict__ A, const float* __restrict__ Bm,
                                                const float* __restrict__ bias, float* __restrict__ C,
                                                int M, int N, int K) {
  __shared__ float As[2][16][68];
  __shared__ float Bs[2][16][64];
  int tid = threadIdx.x;
  int tx = tid & 15, ty = tid >> 4;
  int row0 = blockIdx.y * 64, col0 = blockIdx.x * 64;
  int ar = tid >> 2, ak = (tid & 3) * 4;
  int bkb = tid >> 4, bn = (tid & 15) * 4;
  const float* Aptr = A + (size_t)(row0 + ar) * K + ak;
  const float* Bptr = Bm + (size_t)bkb * N + col0 + bn;
  float4 av = *(const float4*)Aptr;
  float4 bv = *(const float4*)Bptr;
  float acc[4][4] = {};
  int NT = K / 16;
  for (int kt = 0; kt < NT; kt++) {
    int buf = kt & 1;
    As[buf][ak + 0][ar] = av.x; As[buf][ak + 1][ar] = av.y;
    As[buf][ak + 2][ar] = av.z; As[buf][ak + 3][ar] = av.w;
    *(float4*)&Bs[buf][bkb][bn] = bv;
    if (kt + 1 < NT) {
      Aptr += 16; Bptr += (size_t)16 * N;
      av = *(const float4*)Aptr;
      bv = *(const float4*)Bptr;
    }
    __syncthreads();
#pragma unroll
    for (int q = 0; q < 16; q++) {
      float4 a4 = *(const float4*)&As[buf][q][ty * 4];
      float4 b4 = *(const float4*)&Bs[buf][q][tx * 4];
      acc[0][0] += a4.x * b4.x; acc[0][1] += a4.x * b4.y; acc[0][2] += a4.x * b4.z; acc[0][3] += a4.x * b4.w;
      acc[1][0] += a4.y * b4.x; acc[1][1] += a4.y * b4.y; acc[1][2] += a4.y * b4.z; acc[1][3] += a4.y * b4.w;
      acc[2][0] += a4.z * b4.x; acc[2][1] += a4.z * b4.y; acc[2][2] += a4.z * b4.z; acc[2][3] += a4.z * b4.w;
      acc[3][0] += a4.w * b4.x; acc[3][1] += a4.w * b4.y; acc[3][2] += a4.w * b4.z; acc[3][3] += a4.w * b4.w;
    }
  }
#pragma unroll
  for (int i = 0; i < 4; i++)
#pragma unroll
    for (int j = 0; j < 4; j++) {
      int rr = row0 + ty * 4 + i, cc = col0 + tx * 4 + j;
      float v = acc[i][j];
      if (BIAS) v += bias[cc];
      C[(size_t)rr * N + cc] = v;
    }
}

// ---------------- bfused[n] = bih[n] + bhh[n] + dot(Wih[n,:], bc) ----------------
__global__ void bfuse_k(const float* __restrict__ Wih, const float* __restrict__ bc,
                        const float* __restrict__ bih, const float* __restrict__ bhh,
                        float* __restrict__ bf) {
  int n = blockIdx.x * 256 + threadIdx.x;  // < 2048
  float s = bih[n] + bhh[n];
  const float* w = Wih + (size_t)n * 512;
  for (int m = 0; m < 512; m++) s += w[m] * bc[m];
  bf[n] = s;
}

// ---- BTg[2048 cp][1024 k] bf16 hi/lo: BTg[cp][k] = Bcat[k][cp], cp = j*4+g gate-interleaved ----
__global__ void build_btg_k(const float* __restrict__ tmp, const float* __restrict__ Whh,
                            short* __restrict__ hi, short* __restrict__ lo) {
  int idx = blockIdx.x * 256 + threadIdx.x;  // < 2048*1024
  int cp = idx >> 10, k = idx & 1023;
  int j = cp >> 2, g = cp & 3;
  int n = g * 512 + j;
  float v = (k < 512) ? tmp[(size_t)(512 + k) * 2048 + n] : Whh[(size_t)n * 512 + (k - 512)];
  short h = f2bf(v);
  hi[idx] = h;
  lo[idx] = f2bf(v - bf2f(h));
}

// ---- split fp32 -> bf16 hi/lo ----
__global__ void split_k(const float* __restrict__ src, short* __restrict__ hi, short* __restrict__ lo, int n) {
  int i = blockIdx.x * 256 + threadIdx.x;
  if (i < n) {
    float x = src[i];
    short h = f2bf(x);
    hi[i] = h;
    lo[i] = f2bf(x - bf2f(h));
  }
}

// ---- split Wa's h-half (cols 0..511 of [512 x 1024]) to bf16 hi/lo row-major [n][k] ----
__global__ void split_wah_k(const float* __restrict__ Wa, short* __restrict__ hi, short* __restrict__ lo) {
  int idx = blockIdx.x * 256 + threadIdx.x;  // < 512*512
  int n = idx >> 9, k = idx & 511;
  float v = Wa[(size_t)n * 1024 + k];
  short h = f2bf(v);
  hi[idx] = h;
  lo[idx] = f2bf(v - bf2f(h));
}

// ---------------- Gemb_p[96 x 2048] = (emb_table @ tmp[0:512]) + bfused, columns permuted ----------------
__global__ __launch_bounds__(256) void gemb_k(const float* __restrict__ emb_table, const float* __restrict__ tmp,
                                              const float* __restrict__ bfused, float* __restrict__ Gemb_p) {
  __shared__ float emb_s[4][512];
  int tid = threadIdx.x;
  int n0 = blockIdx.x * 256;
  int e0 = blockIdx.y * 4;
  for (int i = tid; i < 2048; i += 256)
    emb_s[i >> 9][i & 511] = emb_table[(size_t)(e0 + (i >> 9)) * 512 + (i & 511)];
  __syncthreads();
  int n = n0 + tid;
  float acc[4] = {};
  for (int k = 0; k < 512; k++) {
    float w = tmp[(size_t)k * 2048 + n];
#pragma unroll
    for (int e = 0; e < 4; e++) acc[e] += emb_s[e][k] * w;
  }
  int cp = (n & 511) * 4 + (n >> 9);
  float b = bfused[n];
#pragma unroll
  for (int e = 0; e < 4; e++) Gemb_p[(size_t)(e0 + e) * 2048 + cp] = acc[e] + b;
}

// ---------------- Za[96 x 512] = emb_table @ WaT_emb + ba ----------------
__global__ __launch_bounds__(256) void za_k(const float* __restrict__ emb_table, const float* __restrict__ WaT_emb,
                                            const float* __restrict__ ba, float* __restrict__ Za) {
  __shared__ float emb_s[4][512];
  int tid = threadIdx.x;
  int n0 = blockIdx.x * 256;
  int e0 = blockIdx.y * 4;
  for (int i = tid; i < 2048; i += 256)
    emb_s[i >> 9][i & 511] = emb_table[(size_t)(e0 + (i >> 9)) * 512 + (i & 511)];
  __syncthreads();
  int n = n0 + tid;
  float acc[4] = {};
  for (int k = 0; k < 512; k++) {
    float w = WaT_emb[(size_t)k * 512 + n];
#pragma unroll
    for (int e = 0; e < 4; e++) acc[e] += emb_s[e][k] * w;
  }
  float b = ba[n];
#pragma unroll
  for (int e = 0; e < 4; e++) Za[(size_t)(e0 + e) * 512 + n] = acc[e] + b;
}

// ---- feats: C[32768x512] = features @ Wfc^T (+bfc). XCD/temporal-swizzled linear grid (4096). ----
__global__ __launch_bounds__(256) void feats_mfma_k(const float* __restrict__ A,
                                                    const short* __restrict__ BTh, const short* __restrict__ BTl,
                                                    const float* __restrict__ bias, float* __restrict__ C) {
  __shared__ short Ah[2][64][40], Al[2][64][40], Bh[2][64][40], Bl[2][64][40];
  int blk = blockIdx.x;
  int xt = (blk >> 3) & 7;
  int ytile = (blk >> 6) * 8 + (blk & 7);
  int row0 = ytile * 64, col0 = xt * 64;
  int tid = threadIdx.x;
  int lane = tid & 63, wave = tid >> 6;
  int wm = (wave & 1) * 32, wn = (wave >> 1) * 32;
  int r15 = lane & 15, q8 = (lane >> 4) * 8;
  int sm = tid >> 2, sk = (tid & 3) * 8;
  const float* Ap = A + (size_t)(row0 + sm) * 512 + sk;
  const short* Bhp = BTh + (size_t)(col0 + sm) * 512 + sk;
  const short* Blp = BTl + (size_t)(col0 + sm) * 512 + sk;
  float4 a0 = *(const float4*)Ap, a1 = *(const float4*)(Ap + 4);
  bf8 bh = *(const bf8*)Bhp, bl = *(const bf8*)Blp;
  f4 acc[2][2] = {};
  for (int kt = 0; kt < 16; kt++) {
    int buf = kt & 1;
    {
      float av[8] = {a0.x, a0.y, a0.z, a0.w, a1.x, a1.y, a1.z, a1.w};
      bf8 ahv, alv;
#pragma unroll
      for (int i = 0; i < 8; i++) {
        short h = f2bf(av[i]);
        ahv[i] = h;
        alv[i] = f2bf(av[i] - bf2f(h));
      }
      *(bf8*)&Ah[buf][sm][sk] = ahv;
      *(bf8*)&Al[buf][sm][sk] = alv;
      *(bf8*)&Bh[buf][sm][sk] = bh;
      *(bf8*)&Bl[buf][sm][sk] = bl;
    }
    if (kt + 1 < 16) {
      Ap += 32; Bhp += 32; Blp += 32;
      a0 = *(const float4*)Ap; a1 = *(const float4*)(Ap + 4);
      bh = *(const bf8*)Bhp; bl = *(const bf8*)Blp;
    }
    __syncthreads();
    bf8 fah[2], fal[2], fbh[2], fbl[2];
#pragma unroll
    for (int r = 0; r < 2; r++) {
      fah[r] = *(const bf8*)&Ah[buf][wm + r * 16 + r15][q8];
      fal[r] = *(const bf8*)&Al[buf][wm + r * 16 + r15][q8];
    }
#pragma unroll
    for (int c = 0; c < 2; c++) {
      fbh[c] = *(const bf8*)&Bh[buf][wn + c * 16 + r15][q8];
      fbl[c] = *(const bf8*)&Bl[buf][wn + c * 16 + r15][q8];
    }
#pragma unroll
    for (int r = 0; r < 2; r++)
#pragma unroll
      for (int c = 0; c < 2; c++) {
        acc[r][c] = __builtin_amdgcn_mfma_f32_16x16x32_bf16(fah[r], fbh[c], acc[r][c], 0, 0, 0);
        acc[r][c] = __builtin_amdgcn_mfma_f32_16x16x32_bf16(fal[r], fbh[c], acc[r][c], 0, 0, 0);
        acc[r][c] = __builtin_amdgcn_mfma_f32_16x16x32_bf16(fah[r], fbl[c], acc[r][c], 0, 0, 0);
      }
  }
#pragma unroll
  for (int r = 0; r < 2; r++)
#pragma unroll
    for (int c = 0; c < 2; c++) {
      int col = col0 + wn + c * 16 + r15;
      float bv = bias[col];
#pragma unroll
      for (int i = 0; i < 4; i++) {
        int row = row0 + wm + r * 16 + (lane >> 4) * 4 + i;
        C[(size_t)row * 512 + col] = acc[r][c][i] + bv;
      }
    }
}

// ---- per-step z GEMM: zbuf[512x512] = h_prev @ WaH^T, split-bf16 MFMA, PRE-SPLIT h input ----
// grid (8,16), 256 thr, tile 32x64.
__global__ __launch_bounds__(256) void z_mfma_k(const short* __restrict__ h_hi, const short* __restrict__ h_lo,
                                                const short* __restrict__ BTh, const short* __restrict__ BTl,
                                                float* __restrict__ zbuf) {
  __shared__ short Ah[2][32][40], Al[2][32][40], Bh[2][64][40], Bl[2][64][40];
  int tid = threadIdx.x;
  int lane = tid & 63, wave = tid >> 6;
  int wm = (wave & 1) * 16, wn = (wave >> 1) * 32;
  int r15 = lane & 15, q4 = (lane >> 4) * 4, q8 = (lane >> 4) * 8;
  int row0 = blockIdx.y * 32, col0 = blockIdx.x * 64;
  int smA = tid >> 3, skA = (tid & 7) * 4;
  int smB = tid >> 2, skB = (tid & 3) * 8;
  const short* ahp = h_hi + (size_t)(row0 + smA) * 512 + skA;
  const short* alp = h_lo + (size_t)(row0 + smA) * 512 + skA;
  const short* Bhp = BTh + (size_t)(col0 + smB) * 512 + skB;
  const short* Blp = BTl + (size_t)(col0 + smB) * 512 + skB;
  bfv4 ah = *(const bfv4*)ahp, al = *(const bfv4*)alp;
  bf8 bh = *(const bf8*)Bhp, bl = *(const bf8*)Blp;
  f4 acc[2] = {};
  for (int kt = 0; kt < 16; kt++) {
    int buf = kt & 1;
    *(bfv4*)&Ah[buf][smA][skA] = ah;
    *(bfv4*)&Al[buf][smA][skA] = al;
    *(bf8*)&Bh[buf][smB][skB] = bh;
    *(bf8*)&Bl[buf][smB][skB] = bl;
    if (kt + 1 < 16) {
      ahp += 32; alp += 32; Bhp += 32; Blp += 32;
      ah = *(const bfv4*)ahp; al = *(const bfv4*)alp;
      bh = *(const bf8*)Bhp; bl = *(const bf8*)Blp;
    }
    __syncthreads();
    bf8 fah = *(const bf8*)&Ah[buf][wm + r15][q8];
    bf8 fal = *(const bf8*)&Al[buf][wm + r15][q8];
#pragma unroll
    for (int c = 0; c < 2; c++) {
      bf8 fbh = *(const bf8*)&Bh[buf][wn + c * 16 + r15][q8];
      bf8 fbl = *(const bf8*)&Bl[buf][wn + c * 16 + r15][q8];
      acc[c] = __builtin_amdgcn_mfma_f32_16x16x32_bf16(fah, fbh, acc[c], 0, 0, 0);
      acc[c] = __builtin_amdgcn_mfma_f32_16x16x32_bf16(fal, fbh, acc[c], 0, 0, 0);
      acc[c] = __builtin_amdgcn_mfma_f32_16x16x32_bf16(fah, fbl, acc[c], 0, 0, 0);
    }
  }
#pragma unroll
  for (int c = 0; c < 2; c++) {
    int col = col0 + wn + c * 16 + r15;
#pragma unroll
    for (int i = 0; i < 4; i++)
      zbuf[(size_t)(row0 + wm + q4 + i) * 512 + col] = acc[c][i];
  }
}

// ---- attn finish: softmax(z+Za[id]) -> scores -> softmax(P) -> ctx (written as bf16 hi/lo). ----
__global__ __launch_bounds__(512) void attn_fin_k(const float* __restrict__ zbuf,
                                                  const int* __restrict__ targets, int t, int T,
                                                  const float* __restrict__ Za, const float* __restrict__ feats,
                                                  short* __restrict__ ctx_hi, short* __restrict__ ctx_lo) {
  __shared__ __align__(16) float z_s[2][512];
  __shared__ float redm[8], reds[8];
  __shared__ float sc_s[2][64];
  __shared__ float w_s[2][64];
  int tid = threadIdx.x;
  int wid = tid >> 6, lane = tid & 63;
  int b0 = blockIdx.x * 2;
  int id0 = (t == 0) ? 0 : targets[b0 * T + t - 1];
  int id1 = (t == 0) ? 0 : targets[(b0 + 1) * T + t - 1];

  // --- softmax over hid (row r = tid>>8, 4 waves/row, 2 cols each) ---
  {
    int r = tid >> 8;
    int nn = tid & 255;
    int idr = r ? id1 : id0;
    const float* zrow = zbuf + (size_t)(b0 + r) * 512;
    const float* za = Za + (size_t)idr * 512;
    float zv0 = zrow[nn] + za[nn];
    float zv1 = zrow[nn + 256] + za[nn + 256];
    float m = fmaxf(zv0, zv1);
#pragma unroll
    for (int off = 32; off; off >>= 1) m = fmaxf(m, __shfl_xor(m, off, 64));
    if (lane == 0) redm[wid] = m;
    __syncthreads();
    float M = fmaxf(fmaxf(redm[r * 4], redm[r * 4 + 1]), fmaxf(redm[r * 4 + 2], redm[r * 4 + 3]));
    float e0 = expf(zv0 - M), e1 = expf(zv1 - M);
    float s = e0 + e1;
#pragma unroll
    for (int off = 32; off; off >>= 1) s += __shfl_xor(s, off, 64);
    if (lane == 0) reds[wid] = s;
    __syncthreads();
    float S = reds[r * 4] + reds[r * 4 + 1] + reds[r * 4 + 2] + reds[r * 4 + 3];
    float inv = 1.f / S;
    z_s[r][nn] = e0 * inv;
    z_s[r][nn + 256] = e1 * inv;
  }
  __syncthreads();

  // --- scores: 128 tasks (r,p), 16 per wave ---
#pragma unroll 1
  for (int q = 0; q < 16; q++) {
    int task = wid * 16 + q;
    int r = task >> 6, p = task & 63;
    const float4* fp = (const float4*)(feats + ((size_t)(b0 + r) * PPOS + p) * 512);
    const float4* ap = (const float4*)(z_s[r]);
    float4 f1 = fp[lane], a1 = ap[lane];
    float4 f2 = fp[lane + 64], a2 = ap[lane + 64];
    float d = f1.x * a1.x + f1.y * a1.y + f1.z * a1.z + f1.w * a1.w
            + f2.x * a2.x + f2.y * a2.y + f2.z * a2.z + f2.w * a2.w;
#pragma unroll
    for (int off = 32; off; off >>= 1) d += __shfl_xor(d, off, 64);
    if (lane == 0) sc_s[r][p] = d;
  }
  __syncthreads();

  // --- softmax over P=64 ---
  if (tid < 128) {
    int r = wid;
    float v = sc_s[r][lane];
    float m = v;
#pragma unroll
    for (int off = 32; off; off >>= 1) m = fmaxf(m, __shfl_xor(m, off, 64));
    float e = expf(v - m);
    float s = e;
#pragma unroll
    for (int off = 32; off; off >>= 1) s += __shfl_xor(s, off, 64);
    w_s[r][lane] = e / s;
  }
  __syncthreads();

  // --- ctx, split to bf16 hi/lo for the gates GEMM ---
#pragma unroll 1
  for (int r = 0; r < 2; r++) {
    const float* fb = feats + (size_t)(b0 + r) * PPOS * 512 + tid;
    float acc = 0.f;
#pragma unroll 8
    for (int p = 0; p < 64; p++) acc += w_s[r][p] * fb[(size_t)p * 512];
    short h = f2bf(acc);
    ctx_hi[(size_t)(b0 + r) * 512 + tid] = h;
    ctx_lo[(size_t)(b0 + r) * 512 + tid] = f2bf(acc - bf2f(h));
  }
}

// ---- gates: [ctx|h][512x1024] @ Bcat (+Gemb[id]) -> LSTM. PRE-SPLIT A inputs. grid (32,8), 64x64. ----
__global__ __launch_bounds__(256) void gates_mfma_k(const short* __restrict__ ctx_hi, const short* __restrict__ ctx_lo,
                                                    const short* __restrict__ h_hi_in, const short* __restrict__ h_lo_in,
                                                    const int* __restrict__ targets, int t, int T,
                                                    const short* __restrict__ BTh, const short* __restrict__ BTl,
                                                    const float* __restrict__ Gemb_p,
                                                    float* __restrict__ cbuf, float* __restrict__ h_new,
                                                    short* __restrict__ h_hi_out, short* __restrict__ h_lo_out) {
  __shared__ short Ah[2][64][40], Al[2][64][40], Bh[2][64][40], Bl[2][64][40];
  __shared__ float Cs[64][68];
  int tid = threadIdx.x;
  int lane = tid & 63, wave = tid >> 6;
  int wm = (wave & 1) * 32, wn = (wave >> 1) * 32;
  int r15 = lane & 15, q8 = (lane >> 4) * 8;
  int row0 = blockIdx.y * 64, col0 = blockIdx.x * 64;
  int sm = tid >> 2, sk = (tid & 3) * 8;
  const short* actx_h = ctx_hi + (size_t)(row0 + sm) * 512;
  const short* actx_l = ctx_lo + (size_t)(row0 + sm) * 512;
  const short* ahst_h = h_hi_in + (size_t)(row0 + sm) * 512;
  const short* ahst_l = h_lo_in + (size_t)(row0 + sm) * 512;
  const short* Bhp = BTh + (size_t)(col0 + sm) * 1024 + sk;
  const short* Blp = BTl + (size_t)(col0 + sm) * 1024 + sk;
  bf8 ah = *(const bf8*)(actx_h + sk), al = *(const bf8*)(actx_l + sk);
  bf8 bh = *(const bf8*)Bhp, bl = *(const bf8*)Blp;
  f4 acc[2][2] = {};
  for (int kt = 0; kt < 32; kt++) {
    int buf = kt & 1;
    *(bf8*)&Ah[buf][sm][sk] = ah;
    *(bf8*)&Al[buf][sm][sk] = al;
    *(bf8*)&Bh[buf][sm][sk] = bh;
    *(bf8*)&Bl[buf][sm][sk] = bl;
    if (kt + 1 < 32) {
      int kk = (kt + 1) * 32 + sk;
      if (kk < 512) {
        ah = *(const bf8*)(actx_h + kk);
        al = *(const bf8*)(actx_l + kk);
      } else {
        ah = *(const bf8*)(ahst_h + kk - 512);
        al = *(const bf8*)(ahst_l + kk - 512);
      }
      Bhp += 32; Blp += 32;
      bh = *(const bf8*)Bhp; bl = *(const bf8*)Blp;
    }
    __syncthreads();
    bf8 fah[2], fal[2], fbh[2], fbl[2];
#pragma unroll
    for (int r = 0; r < 2; r++) {
      fah[r] = *(const bf8*)&Ah[buf][wm + r * 16 + r15][q8];
      fal[r] = *(const bf8*)&Al[buf][wm + r * 16 + r15][q8];
    }
#pragma unroll
    for (int c = 0; c < 2; c++) {
      fbh[c] = *(const bf8*)&Bh[buf][wn + c * 16 + r15][q8];
      fbl[c] = *(const bf8*)&Bl[buf][wn + c * 16 + r15][q8];
    }
#pragma unroll
    for (int r = 0; r < 2; r++)
#pragma unroll
      for (int c = 0; c < 2; c++) {
        acc[r][c] = __builtin_amdgcn_mfma_f32_16x16x32_bf16(fah[r], fbh[c], acc[r][c], 0, 0, 0);
        acc[r][c] = __builtin_amdgcn_mfma_f32_16x16x32_bf16(fal[r], fbh[c], acc[r][c], 0, 0, 0);
        acc[r][c] = __builtin_amdgcn_mfma_f32_16x16x32_bf16(fah[r], fbl[c], acc[r][c], 0, 0, 0);
      }
  }
  // stage C tile to LDS (MFMA C layout -> row/col), then LSTM epilogue
#pragma unroll
  for (int r = 0; r < 2; r++)
#pragma unroll
    for (int c = 0; c < 2; c++)
#pragma unroll
      for (int i = 0; i < 4; i++)
        Cs[wm + r * 16 + (lane >> 4) * 4 + i][wn + c * 16 + r15] = acc[r][c][i];
  __syncthreads();
#pragma unroll
  for (int i = 0; i < 4; i++) {
    int idx = i * 256 + tid;
    int row = idx >> 4, jj = idx & 15;
    int b = row0 + row;
    int jg = (col0 >> 2) + jj;
    int id = (t == 0) ? 0 : targets[b * T + t - 1];
    float4 g4 = *(const float4*)(Gemb_p + (size_t)id * 2048 + col0 + jj * 4);
    float ig = sigmoidf_(Cs[row][jj * 4 + 0] + g4.x);
    float fg = sigmoidf_(Cs[row][jj * 4 + 1] + g4.y);
    float gg = tanhf(Cs[row][jj * 4 + 2] + g4.z);
    float og = sigmoidf_(Cs[row][jj * 4 + 3] + g4.w);
    float cn = fg * cbuf[(size_t)b * 512 + jg] + ig * gg;
    float hn = og * tanhf(cn);
    cbuf[(size_t)b * 512 + jg] = cn;
    h_new[(size_t)b * 512 + jg] = hn;
    short hh = f2bf(hn);
    h_hi_out[(size_t)b * 512 + jg] = hh;
    h_lo_out[(size_t)b * 512 + jg] = f2bf(hn - bf2f(hh));
  }
}

// ---------------- final output GEMM over all timesteps ----------------
__global__ __launch_bounds__(256) void out_gemm_k(const float* __restrict__ h_hist, const float* __restrict__ WoT,
                                                  const float* __restrict__ bo, float* __restrict__ out, int T) {
  __shared__ float As[16][68];
  __shared__ float Bs[16][96];
  int tid = threadIdx.x;
  int tx = tid & 15, ty = tid >> 4;
  int row0 = blockIdx.x * 64;
  float acc[4][6] = {};
  for (int k0 = 0; k0 < 512; k0 += 16) {
    {
      int r = tid >> 2;
      int kk = (tid & 3) * 4;
      float4 v = *(const float4*)(h_hist + (size_t)(row0 + r) * 512 + k0 + kk);
      As[kk + 0][r] = v.x; As[kk + 1][r] = v.y; As[kk + 2][r] = v.z; As[kk + 3][r] = v.w;
    }
#pragma unroll
    for (int i = 0; i < 6; i++) {
      int e = tid + 256 * i;
      int kb = e / 96, n = e - kb * 96;
      Bs[kb][n] = WoT[(size_t)(k0 + kb) * 96 + n];
    }
    __syncthreads();
#pragma unroll
    for (int q = 0; q < 16; q++) {
      float av[4], bvv[6];
#pragma unroll
      for (int i = 0; i < 4; i++) av[i] = As[q][ty * 4 + i];
#pragma unroll
      for (int j = 0; j < 6; j++) bvv[j] = Bs[q][tx * 6 + j];
#pragma unroll
      for (int i = 0; i < 4; i++)
#pragma unroll
        for (int j = 0; j < 6; j++) acc[i][j] += av[i] * bvv[j];
    }
    __syncthreads();
  }
#pragma unroll
  for (int i = 0; i < 4; i++)
#pragma unroll
    for (int j = 0; j < 6; j++) {
      int row = row0 + ty * 4 + i;
      int tt = row >> 9, bb = row & 511;
      int cc = tx * 6 + j;
      out[((size_t)bb * T + tt) * 96 + cc] = acc[i][j] + bo[cc];
    }
}

extern "C" void kernel_launch(void* const* d_in, const int* in_sizes, int n_in,
                              void* d_out, int out_size, void* d_ws, size_t ws_size,
                              hipStream_t stream) {
  const float* features  = (const float*)d_in[0];
  const int*   targets   = (const int*)d_in[1];
  const float* Wfc       = (const float*)d_in[3];
  const float* bfc       = (const float*)d_in[4];
  const float* emb_table = (const float*)d_in[5];
  const float* Wa        = (const float*)d_in[6];
  const float* ba        = (const float*)d_in[7];
  const float* Wc        = (const float*)d_in[8];
  const float* bc        = (const float*)d_in[9];
  const float* Wih       = (const float*)d_in[10];
  const float* Whh       = (const float*)d_in[11];
  const float* bih       = (const float*)d_in[12];
  const float* bhh       = (const float*)d_in[13];
  const float* Wo        = (const float*)d_in[14];
  const float* bo        = (const float*)d_in[15];
  float* out = (float*)d_out;
  int T = in_sizes[1] / BATCH;  // 30

  char* base = (char*)d_ws;
  auto alloc = [&](size_t bytes) -> char* {
    char* p = base;
    base += (bytes + 255) & ~(size_t)255;
    return p;
  };
  float* feats   = (float*)alloc((size_t)BATCH * PPOS * HIDC * 4);
  float* WaT_emb = (float*)alloc(512 * 512 * 4);
  float* WcT     = (float*)alloc(1024 * 512 * 4);
  float* WihT    = (float*)alloc(512 * 2048 * 4);
  float* tmp     = (float*)alloc((size_t)1024 * 2048 * 4);
  short* BTg_hi  = (short*)alloc((size_t)2048 * 1024 * 2);
  short* BTg_lo  = (short*)alloc((size_t)2048 * 1024 * 2);
  short* Wfc_hi  = (short*)alloc(512 * 512 * 2);
  short* Wfc_lo  = (short*)alloc(512 * 512 * 2);
  short* WaH_hi  = (short*)alloc(512 * 512 * 2);
  short* WaH_lo  = (short*)alloc(512 * 512 * 2);
  float* Gemb_p  = (float*)alloc(96 * 2048 * 4);
  float* Za      = (float*)alloc(96 * 512 * 4);
  float* bfused  = (float*)alloc(2048 * 4);
  float* WoT     = (float*)alloc(512 * 96 * 4);
  float* cbuf    = (float*)alloc(BATCH * HIDC * 4);
  float* zbuf    = (float*)alloc(BATCH * HIDC * 4);
  short* ctx_hi  = (short*)alloc(BATCH * HIDC * 2);
  short* ctx_lo  = (short*)alloc(BATCH * HIDC * 2);
  short* h_hi    = (short*)alloc(BATCH * HIDC * 2);
  short* h_lo    = (short*)alloc(BATCH * HIDC * 2);
  float* h_hist  = (float*)alloc((size_t)T * BATCH * HIDC * 4);

  dim3 tb(32, 8);
  transpose_k<<<dim3(16, 16), tb, 0, stream>>>(Wa + 512, WaT_emb, 512, 512, 1024);
  transpose_k<<<dim3(32, 16), tb, 0, stream>>>(Wc, WcT, 512, 1024, 1024);
  transpose_k<<<dim3(16, 64), tb, 0, stream>>>(Wih, WihT, 2048, 512, 512);
  transpose_k<<<dim3(16, 3),  tb, 0, stream>>>(Wo, WoT, 96, 512, 512);

  // tmp = WcT[1024x512] @ WihT[512x2048]  ( = (Wih@Wc)^T )
  gemm64_k<false><<<dim3(32, 16), 256, 0, stream>>>(WcT, WihT, nullptr, tmp, 1024, 2048, 512);
  bfuse_k<<<8, 256, 0, stream>>>(Wih, bc, bih, bhh, bfused);
  build_btg_k<<<(2048 * 1024) / 256, 256, 0, stream>>>(tmp, Whh, BTg_hi, BTg_lo);
  gemb_k<<<dim3(8, 24), 256, 0, stream>>>(emb_table, tmp, bfused, Gemb_p);
  za_k<<<dim3(2, 24), 256, 0, stream>>>(emb_table, WaT_emb, ba, Za);
  split_k<<<(512 * 512) / 256, 256, 0, stream>>>(Wfc, Wfc_hi, Wfc_lo, 512 * 512);
  split_wah_k<<<(512 * 512) / 256, 256, 0, stream>>>(Wa, WaH_hi, WaH_lo);

  // feats = features @ Wfc.T + bfc   [32768 x 512], split-bf16 MFMA, XCD-swizzled grid
  feats_mfma_k<<<4096, 256, 0, stream>>>(features, Wfc_hi, Wfc_lo, bfc, feats);

  hipMemsetAsync(cbuf, 0, (size_t)BATCH * HIDC * 4, stream);
  hipMemsetAsync(h_hi, 0, (size_t)BATCH * HIDC * 2, stream);
  hipMemsetAsync(h_lo, 0, (size_t)BATCH * HIDC * 2, stream);

  for (int t = 0; t < T; t++) {
    float* h_new = h_hist + (size_t)t * BATCH * HIDC;
    z_mfma_k<<<dim3(8, 16), 256, 0, stream>>>(h_hi, h_lo, WaH_hi, WaH_lo, zbuf);
    attn_fin_k<<<256, 512, 0, stream>>>(zbuf, targets, t, T, Za, feats, ctx_hi, ctx_lo);
    gates_mfma_k<<<dim3(32, 8), 256, 0, stream>>>(ctx_hi, ctx_lo, h_hi, h_lo, targets, t, T,
                                                  BTg_hi, BTg_lo, Gemb_p, cbuf, h_new, h_hi, h_lo);
  }
  out_gemm_k<<<(T * BATCH) / 64, 256, 0, stream>>>(h_hist, WoT, bo, out, T);
}